// Round 16
// baseline (337.647 us; speedup 1.0000x reference)
//
#include <hip/hip_runtime.h>
#include <hip/hip_bf16.h>

#define B_   8
#define NQ_  1000
#define D_   256
#define NH_  8
#define L_   4
#define P_   4
#define DFF_ 1024
#define HD_  32
#define S_   21760
#define NTOK (B_*NQ_)

typedef short  bf16x8 __attribute__((ext_vector_type(8)));
typedef float  f32x4  __attribute__((ext_vector_type(4)));

#define WAITBAR(N) asm volatile("s_waitcnt vmcnt(" #N ") lgkmcnt(0)\n\ts_barrier" ::: "memory")
#define ENDBAR()   asm volatile("s_barrier" ::: "memory")

__device__ inline unsigned short f32_to_bf16_bits(float f) {
    unsigned int u = __float_as_uint(f);
    unsigned int rounding = 0x7FFFu + ((u >> 16) & 1u);
    u += rounding;
    return (unsigned short)(u >> 16);
}
__device__ inline float bf16_bits_to_f32(unsigned short b) {
    return __uint_as_float(((unsigned int)b) << 16);
}
// {bf16_trunc(f1)<<16 | bf16_trunc(f0)} in ONE v_perm_b32
__device__ inline unsigned int pack_trunc(float f0, float f1) {
    return __builtin_amdgcn_perm(__float_as_uint(f1), __float_as_uint(f0), 0x07060302u);
}
__device__ inline void async_copy16(const void* g, void* l) {
    __builtin_amdgcn_global_load_lds((const __attribute__((address_space(1))) unsigned int*)g,
                                     (__attribute__((address_space(3))) unsigned int*)l, 16, 0, 0);
}

// ============================================================================
// Value-projection GEMM body (r14-verified vgemmF), callable from fused
// kernels. Consumes fp32 A directly via global_load_lds (fused f32->bf16 on
// fragment read), B bf16 dbuf, counted WAITBAR(6). 48KB smem.
// vbid in [0,2720): n0 = (vbid&1)*128, m0 = (vbid>>1)*128.
// ============================================================================
struct VArgs {
    const float* Af;
    const unsigned short* Bt;
    const float* bias;
    unsigned short* Cb;
};

__device__ inline void vgemm_body(char* smem, int vbid, const VArgs V)
{
    constexpr int K = 256;
    constexpr int N = 256;
    float* sA0 = reinterpret_cast<float*>(smem);                         // 2 x 16KB
    unsigned short* sB0 = reinterpret_cast<unsigned short*>(smem + 32768); // 2 x 8KB

    const int tid = threadIdx.x;
    const int w = tid >> 6, l = tid & 63;
    const int n0 = (vbid & 1) * 128, m0 = (vbid >> 1) * 128;
    const int wr = w >> 1, wc = w & 1;
    const int lq = l & 15, g = l >> 4;

    f32x4 acc[4][4];
    #pragma unroll
    for (int i = 0; i < 4; i++)
        #pragma unroll
        for (int j = 0; j < 4; j++)
            #pragma unroll
            for (int r = 0; r < 4; r++) acc[i][j][r] = 0.f;

    auto issueA = [&](int t, int buf) {
        #pragma unroll
        for (int r = 0; r < 4; r++) {
            int lin = (r * 256 + tid) * 16;
            int row = lin >> 7;
            int kb  = (lin & 127) ^ ((row & 7) << 4);
            async_copy16(V.Af + (size_t)(m0 + row) * K + t * 32 + (kb >> 2),
                         (char*)(sA0 + (size_t)buf * 4096) + lin);
        }
    };
    auto issueB = [&](int t, int buf) {
        #pragma unroll
        for (int r = 0; r < 2; r++) {
            int lin = (r * 256 + tid) * 16;
            int row = lin >> 6;
            int kb  = (lin & 63) ^ ((row & 3) << 4);
            async_copy16(V.Bt + (size_t)(n0 + row) * K + t * 32 + (kb >> 1),
                         (char*)(sB0 + (size_t)buf * 4096) + lin);
        }
    };

    issueA(0, 0);
    issueB(0, 0);

    for (int t = 0; t < 8; t++) {
        const int cur = t & 1;
        if (t + 1 < 8) {
            issueA(t + 1, cur ^ 1);
            issueB(t + 1, cur ^ 1);
            WAITBAR(6);
        } else {
            WAITBAR(0);
        }

        const float* sA = sA0 + (size_t)cur * 4096;
        const unsigned short* sB = sB0 + (size_t)cur * 4096;
        bf16x8 afr[4], bfr[4];
        #pragma unroll
        for (int mi = 0; mi < 4; mi++) {
            int row = wr * 64 + mi * 16 + lq;
            int sw  = (row & 7) << 4;
            int p0  = (g * 32) ^ sw;
            const char* p = (const char*)sA + row * 128;
            float4 a0 = *reinterpret_cast<const float4*>(p + p0);
            float4 a1 = *reinterpret_cast<const float4*>(p + (p0 ^ 16));
            uint4 u;
            u.x = pack_trunc(a0.x, a0.y);
            u.y = pack_trunc(a0.z, a0.w);
            u.z = pack_trunc(a1.x, a1.y);
            u.w = pack_trunc(a1.z, a1.w);
            afr[mi] = *reinterpret_cast<bf16x8*>(&u);
        }
        #pragma unroll
        for (int ni = 0; ni < 4; ni++) {
            int row = wc * 64 + ni * 16 + lq;
            int off = (g * 16) ^ ((row & 3) << 4);
            bfr[ni] = *reinterpret_cast<const bf16x8*>((const char*)sB + row * 64 + off);
        }
        #pragma unroll
        for (int mi = 0; mi < 4; mi++)
            #pragma unroll
            for (int ni = 0; ni < 4; ni++)
                acc[mi][ni] = __builtin_amdgcn_mfma_f32_16x16x32_bf16(
                    afr[mi], bfr[ni], acc[mi][ni], 0, 0, 0);
        ENDBAR();
    }

    #pragma unroll
    for (int mi = 0; mi < 4; mi++) {
        #pragma unroll
        for (int ni = 0; ni < 4; ni++) {
            int col = n0 + wc * 64 + ni * 16 + lq;
            float bz = V.bias[col];
            #pragma unroll
            for (int rg = 0; rg < 4; rg++) {
                int row = m0 + wr * 64 + mi * 16 + g * 4 + rg;
                V.Cb[(size_t)row * N + col] = f32_to_bf16_bits(acc[mi][ni][rg] + bz);
            }
        }
    }
}

// ============================================================================
// Fused prep (r14): weights 0..639, bias 640, q/qp 641..890.
// ============================================================================
struct PrepArgs {
    const float* wsrc[10];
    unsigned short* wdst[10];
    int wK[10], wN[10];
    const float* bq; const float* bk; const float* bv; const float* boff; const float* battn;
    float* qkvb; float* oab;
    const float* query; const float* qpos;
    unsigned short* q_bf; unsigned short* qp_bf;
};
__global__ __launch_bounds__(256) void prep_k(PrepArgs P)
{
    const int bid = blockIdx.x, tid = threadIdx.x;
    if (bid < 640) {
        const int job = bid >> 6, tile = bid & 63;
        const int K = P.wK[job], N = P.wN[job];
        const int tilesN = N >> 6;
        if (tile >= (K >> 6) * tilesN) return;
        const int kt = tile / tilesN, nt = tile - kt * tilesN;
        const int k0 = kt * 64, n0 = nt * 64;
        __shared__ unsigned short t_[64][65];
        const float* src = P.wsrc[job];
        unsigned short* dst = P.wdst[job];
        const int cc = tid & 63, rr = tid >> 6;
        #pragma unroll
        for (int i = 0; i < 16; i++) {
            int k = i * 4 + rr;
            t_[k][cc] = f32_to_bf16_bits(src[(size_t)(k0 + k) * N + n0 + cc]);
        }
        __syncthreads();
        #pragma unroll
        for (int i = 0; i < 16; i++) {
            int n = i * 4 + rr;
            dst[(size_t)(n0 + n) * K + k0 + cc] = t_[cc][n];
        }
    } else if (bid == 640) {
        P.qkvb[tid]       = P.bq[tid];
        P.qkvb[256 + tid] = P.bk[tid];
        P.qkvb[512 + tid] = P.bv[tid];
        P.oab[tid]        = P.boff[tid];
        if (tid < 128) P.oab[256 + tid] = P.battn[tid];
    } else {
        const int base = (bid - 641) * 1024 + tid;
        float4 fq[4][2], fp[4][2];
        #pragma unroll
        for (int i = 0; i < 4; i++) {
            const float* q = P.query + (size_t)(base + i * 256) * 8;
            const float* p = P.qpos  + (size_t)(base + i * 256) * 8;
            fq[i][0] = *reinterpret_cast<const float4*>(q);
            fq[i][1] = *reinterpret_cast<const float4*>(q + 4);
            fp[i][0] = *reinterpret_cast<const float4*>(p);
            fp[i][1] = *reinterpret_cast<const float4*>(p + 4);
        }
        #pragma unroll
        for (int i = 0; i < 4; i++) {
            uint4 tq, tp;
            tq.x = pack_trunc(fq[i][0].x, fq[i][0].y);
            tq.y = pack_trunc(fq[i][0].z, fq[i][0].w);
            tq.z = pack_trunc(fq[i][1].x, fq[i][1].y);
            tq.w = pack_trunc(fq[i][1].z, fq[i][1].w);
            tp.x = pack_trunc(fq[i][0].x + fp[i][0].x, fq[i][0].y + fp[i][0].y);
            tp.y = pack_trunc(fq[i][0].z + fp[i][0].z, fq[i][0].w + fp[i][0].w);
            tp.z = pack_trunc(fq[i][1].x + fp[i][1].x, fq[i][1].y + fp[i][1].y);
            tp.w = pack_trunc(fq[i][1].z + fp[i][1].z, fq[i][1].w + fp[i][1].w);
            *reinterpret_cast<uint4*>(P.q_bf  + (size_t)(base + i * 256) * 8) = tq;
            *reinterpret_cast<uint4*>(P.qp_bf + (size_t)(base + i * 256) * 8) = tp;
        }
    }
}

// ============================================================================
// FUSED: q/k/v projection (blocks 0..1499) + vgemmF slice [0,654).
// ============================================================================
__global__ __launch_bounds__(256) void qkvF(const unsigned short* __restrict__ qp_bf,
                                            const unsigned short* __restrict__ q_bf,
                                            const unsigned short* __restrict__ Bt,
                                            const float* __restrict__ bias,
                                            unsigned short* __restrict__ qk_out,
                                            unsigned short* __restrict__ vt_out,
                                            VArgs V)
{
    __shared__ __align__(16) char smem[49152];
    const int bid = blockIdx.x;
    if (bid >= 1500) { vgemm_body(smem, bid - 1500, V); return; }

    constexpr int K = 256;
    unsigned short* sB = reinterpret_cast<unsigned short*>(smem);  // 32KB

    const int tid = threadIdx.x;
    const int w = tid >> 6, l = tid & 63;
    const int g = l >> 4, lr = l & 15;
    const int n0 = (bid % 12) * 64;
    const int my = bid / 12;
    const bool isV = (n0 >= 512);
    const unsigned short* Ab = isV ? q_bf : qp_bf;

    #pragma unroll
    for (int r = 0; r < 8; r++) {
        int lin = (r * 256 + tid) * 16;
        int row = lin >> 9;
        int kb  = (lin & 511) ^ ((row & 7) << 4);
        async_copy16(Bt + (size_t)(n0 + row) * K + (kb >> 1), (char*)sB + lin);
    }
    asm volatile("s_waitcnt vmcnt(0)\n\ts_barrier" ::: "memory");

    float bz[4];
    #pragma unroll
    for (int nf = 0; nf < 4; nf++) bz[nf] = bias[n0 + nf * 16 + lr];

    const int m0w = my * 64 + w * 16;
    const int arow = m0w + lr;

    f32x4 acc[4];
    #pragma unroll
    for (int nf = 0; nf < 4; nf++)
        #pragma unroll
        for (int r = 0; r < 4; r++) acc[nf][r] = 0.f;

    #pragma unroll
    for (int kf = 0; kf < 8; kf++) {
        bf16x8 af = *reinterpret_cast<const bf16x8*>(Ab + (size_t)arow * K + kf * 32 + g * 8);
        #pragma unroll
        for (int nf = 0; nf < 4; nf++) {
            int brow = nf * 16 + lr;
            bf16x8 bf = *reinterpret_cast<const bf16x8*>(
                (const char*)sB + brow * 512 + ((kf * 64 + g * 16) ^ ((brow & 7) << 4)));
            acc[nf] = __builtin_amdgcn_mfma_f32_16x16x32_bf16(af, bf, acc[nf], 0, 0, 0);
        }
    }

    if (!isV) {
        #pragma unroll
        for (int nf = 0; nf < 4; nf++) {
            int col = n0 + nf * 16 + lr;
            #pragma unroll
            for (int rg = 0; rg < 4; rg++) {
                int row = m0w + g * 4 + rg;
                qk_out[(size_t)row * 512 + col] = f32_to_bf16_bits(acc[nf][rg] + bz[nf]);
            }
        }
    } else {
        #pragma unroll
        for (int nf = 0; nf < 4; nf++) {
            int col = n0 - 512 + nf * 16 + lr;
            int row0 = m0w + g * 4;
            int bb = row0 / 1000;
            int key = row0 - bb * 1000;
            ushort4 q4;
            q4.x = f32_to_bf16_bits(acc[nf][0] + bz[nf]);
            q4.y = f32_to_bf16_bits(acc[nf][1] + bz[nf]);
            q4.z = f32_to_bf16_bits(acc[nf][2] + bz[nf]);
            q4.w = f32_to_bf16_bits(acc[nf][3] + bz[nf]);
            *reinterpret_cast<ushort4*>(vt_out + (size_t)bb * 262144 + (size_t)col * 1024 + key) = q4;
        }
    }
}

// ============================================================================
// FUSED: flash self-attention (blocks 0..1023) + vgemmF slice [654,1700).
// ============================================================================
__global__ __launch_bounds__(256) void fattnF(const unsigned short* __restrict__ qk,
                                              const unsigned short* __restrict__ vt,
                                              unsigned short* __restrict__ sa,
                                              VArgs V)
{
    __shared__ __align__(16) char smem[49152];
    const int bid = blockIdx.x;
    if (bid >= 1024) { vgemm_body(smem, 654 + bid - 1024, V); return; }

    unsigned short* Ks0 = reinterpret_cast<unsigned short*>(smem);            // 2 x 8KB
    unsigned short* Vs0 = reinterpret_cast<unsigned short*>(smem + 16384);    // 2 x 8KB
    unsigned short* Ps  = reinterpret_cast<unsigned short*>(smem + 32768);    // 4 x 4KB

    const int b = bid >> 7, h = (bid >> 4) & 7;
    const int tid = threadIdx.x;
    const int w = tid >> 6, l = tid & 63;
    const int lq = l & 15, g = l >> 4;
    const int q0 = (bid & 15) * 64 + w * 16;

    int qrow = q0 + lq; if (qrow > NQ_ - 1) qrow = NQ_ - 1;
    const bf16x8 qfrag = *reinterpret_cast<const bf16x8*>(
        qk + ((size_t)(b * NQ_ + qrow)) * 512 + h * 32 + g * 8);

    f32x4 O0 = {0.f, 0.f, 0.f, 0.f}, O1 = {0.f, 0.f, 0.f, 0.f};
    float m = -1e30f, lsum = 0.f;
    const float scale = 0.17677669529663687f;

    const size_t kbase = (size_t)b * (NQ_ * 512) + 256 + h * 32;
    const size_t vbase = (size_t)b * 262144 + (size_t)(h * 32) * 1024;
    const int swz = (lq & 7) << 4;

    auto issueKV = [&](int kt, int buf) {
        #pragma unroll
        for (int r = 0; r < 2; r++) {
            int lin = (r * 256 + tid) * 16;
            int krow = lin >> 6;
            int kb = (lin & 63) ^ ((krow & 7) << 4);
            async_copy16(qk + kbase + (size_t)(kt * 128 + krow) * 512 + (kb >> 1),
                         (char*)(Ks0 + (size_t)buf * 4096) + lin);
            int d = lin >> 8;
            int vb = (lin & 255) ^ ((d & 7) << 4);
            async_copy16(vt + vbase + (size_t)d * 1024 + kt * 128 + (vb >> 1),
                         (char*)(Vs0 + (size_t)buf * 4096) + lin);
        }
    };

    issueKV(0, 0);

    for (int kt = 0; kt < 8; kt++) {
        const int k0 = kt * 128;
        const int cur = kt & 1;
        asm volatile("s_waitcnt vmcnt(0) lgkmcnt(0)\n\ts_barrier" ::: "memory");
        if (kt < 7) issueKV(kt + 1, cur ^ 1);

        const unsigned short* Kc = Ks0 + (size_t)cur * 4096;
        const unsigned short* Vc = Vs0 + (size_t)cur * 4096;

        float t[8][4];
        float tmax = -1e30f;
        const bool tail = (k0 + 128 > NQ_);
        #pragma unroll
        for (int ni = 0; ni < 8; ni++) {
            int row = ni * 16 + lq;
            bf16x8 kf = *reinterpret_cast<const bf16x8*>(
                (const char*)Kc + row * 64 + ((g * 16) ^ swz));
            f32x4 st = __builtin_amdgcn_mfma_f32_16x16x32_bf16(
                kf, qfrag, (f32x4){0.f, 0.f, 0.f, 0.f}, 0, 0, 0);
            #pragma unroll
            for (int rg = 0; rg < 4; rg++) {
                float tv = st[rg] * scale;
                if (tail) {
                    int key = k0 + ni * 16 + g * 4 + rg;
                    tv = (key < NQ_) ? tv : -1e30f;
                }
                t[ni][rg] = tv;
                tmax = fmaxf(tmax, tv);
            }
        }
        tmax = fmaxf(tmax, __shfl_xor(tmax, 16));
        tmax = fmaxf(tmax, __shfl_xor(tmax, 32));
        float mnew = fmaxf(m, tmax);
        float corr = __expf(m - mnew);
        m = mnew;

        float rs = 0.f;
        unsigned int pk[8][2];
        #pragma unroll
        for (int ni = 0; ni < 8; ni++) {
            float p0 = __expf(t[ni][0] - mnew);
            float p1 = __expf(t[ni][1] - mnew);
            float p2 = __expf(t[ni][2] - mnew);
            float p3 = __expf(t[ni][3] - mnew);
            rs += (p0 + p1) + (p2 + p3);
            pk[ni][0] = ((unsigned)f32_to_bf16_bits(p0)) | (((unsigned)f32_to_bf16_bits(p1)) << 16);
            pk[ni][1] = ((unsigned)f32_to_bf16_bits(p2)) | (((unsigned)f32_to_bf16_bits(p3)) << 16);
        }
        rs += __shfl_xor(rs, 16);
        rs += __shfl_xor(rs, 32);
        lsum = lsum * corr + rs;

        float c0 = __shfl(corr, g * 4 + 0);
        float c1 = __shfl(corr, g * 4 + 1);
        float c2 = __shfl(corr, g * 4 + 2);
        float c3 = __shfl(corr, g * 4 + 3);
        O0[0] *= c0; O0[1] *= c1; O0[2] *= c2; O0[3] *= c3;
        O1[0] *= c0; O1[1] *= c1; O1[2] *= c2; O1[3] *= c3;

        unsigned short* Pw = Ps + (size_t)w * 2048;
        #pragma unroll
        for (int ni = 0; ni < 8; ni++) {
            int byteoff = lq * 256 + ((ni * 32 + g * 8) ^ swz);
            *reinterpret_cast<uint2*>((char*)Pw + byteoff) = make_uint2(pk[ni][0], pk[ni][1]);
        }

        #pragma unroll
        for (int c = 0; c < 4; c++) {
            int rb = (c * 64 + g * 16) ^ swz;
            bf16x8 pa = *reinterpret_cast<const bf16x8*>((const char*)Pw + lq * 256 + rb);
            bf16x8 v0 = *reinterpret_cast<const bf16x8*>((const char*)Vc + lq * 256 + rb);
            bf16x8 v1 = *reinterpret_cast<const bf16x8*>((const char*)Vc + (16 + lq) * 256 + rb);
            O0 = __builtin_amdgcn_mfma_f32_16x16x32_bf16(pa, v0, O0, 0, 0, 0);
            O1 = __builtin_amdgcn_mfma_f32_16x16x32_bf16(pa, v1, O1, 0, 0, 0);
        }
    }

    float linv = 1.f / lsum;
    float i0 = __shfl(linv, g * 4 + 0);
    float i1 = __shfl(linv, g * 4 + 1);
    float i2 = __shfl(linv, g * 4 + 2);
    float i3 = __shfl(linv, g * 4 + 3);
    float iv[4] = {i0, i1, i2, i3};
    #pragma unroll
    for (int rg = 0; rg < 4; rg++) {
        int qg = q0 + g * 4 + rg;
        if (qg < NQ_) {
            size_t obase = ((size_t)(b * NQ_ + qg)) * 256 + h * 32;
            sa[obase + lq]      = f32_to_bf16_bits(O0[rg] * iv[rg]);
            sa[obase + 16 + lq] = f32_to_bf16_bits(O1[rg] * iv[rg]);
        }
    }
}

// ============================================================================
// FUSED: sa @ Wo GEMM (blocks 0..499) + vgemmF slice [1700,2223).
// ============================================================================
__global__ __launch_bounds__(256) void woF(const unsigned short* __restrict__ Ab,
                                           const unsigned short* __restrict__ Bt,
                                           const float* __restrict__ bias,
                                           float* __restrict__ Cf,
                                           VArgs V)
{
    __shared__ __align__(16) char smem[49152];
    const int bid = blockIdx.x;
    if (bid >= 500) { vgemm_body(smem, 1700 + bid - 500, V); return; }

    constexpr int K = 256;
    unsigned short* sB = reinterpret_cast<unsigned short*>(smem);  // 32KB

    const int tid = threadIdx.x;
    const int w = tid >> 6, l = tid & 63;
    const int g = l >> 4, lr = l & 15;
    const int n0 = (bid & 3) * 64;
    const int my = bid >> 2;

    #pragma unroll
    for (int r = 0; r < 8; r++) {
        int lin = (r * 256 + tid) * 16;
        int row = lin >> 9;
        int kb  = (lin & 511) ^ ((row & 7) << 4);
        async_copy16(Bt + (size_t)(n0 + row) * K + (kb >> 1), (char*)sB + lin);
    }
    asm volatile("s_waitcnt vmcnt(0)\n\ts_barrier" ::: "memory");

    float bz[4];
    #pragma unroll
    for (int nf = 0; nf < 4; nf++) bz[nf] = bias[n0 + nf * 16 + lr];

    const int m0w = my * 64 + w * 16;
    const int arow = m0w + lr;

    f32x4 acc[4];
    #pragma unroll
    for (int nf = 0; nf < 4; nf++)
        #pragma unroll
        for (int r = 0; r < 4; r++) acc[nf][r] = 0.f;

    #pragma unroll
    for (int kf = 0; kf < 8; kf++) {
        bf16x8 af = *reinterpret_cast<const bf16x8*>(Ab + (size_t)arow * K + kf * 32 + g * 8);
        #pragma unroll
        for (int nf = 0; nf < 4; nf++) {
            int brow = nf * 16 + lr;
            bf16x8 bf = *reinterpret_cast<const bf16x8*>(
                (const char*)sB + brow * 512 + ((kf * 64 + g * 16) ^ ((brow & 7) << 4)));
            acc[nf] = __builtin_amdgcn_mfma_f32_16x16x32_bf16(af, bf, acc[nf], 0, 0, 0);
        }
    }

    #pragma unroll
    for (int nf = 0; nf < 4; nf++) {
        int col = n0 + nf * 16 + lr;
        #pragma unroll
        for (int rg = 0; rg < 4; rg++) {
            int row = m0w + g * 4 + rg;
            Cf[(size_t)row * 256 + col] = acc[nf][rg] + bz[nf];
        }
    }
}

// ============================================================================
// FUSED: LN1 (OM=2 behavior; blocks 0..1999) + vgemmF slice [2223,2720).
// ============================================================================
__global__ __launch_bounds__(256) void ln1F(const float* __restrict__ a,
                                            const float* __restrict__ bsum,
                                            const float* __restrict__ pos,
                                            const float* __restrict__ g,
                                            const float* __restrict__ be,
                                            float* __restrict__ out,
                                            unsigned short* __restrict__ outb,
                                            VArgs V)
{
    __shared__ __align__(16) char smem[49152];
    const int bid = blockIdx.x;
    if (bid >= 2000) { vgemm_body(smem, 2223 + bid - 2000, V); return; }

    const int wave = threadIdx.x >> 6, lane = threadIdx.x & 63;
    const int row = bid * 4 + wave;
    float4 xa = reinterpret_cast<const float4*>(a + (size_t)row * 256)[lane];
    float4 xb = reinterpret_cast<const float4*>(bsum + (size_t)row * 256)[lane];
    float4 x = {xa.x + xb.x, xa.y + xb.y, xa.z + xb.z, xa.w + xb.w};
    float s  = x.x + x.y + x.z + x.w;
    float ss = x.x * x.x + x.y * x.y + x.z * x.z + x.w * x.w;
    #pragma unroll
    for (int off = 32; off > 0; off >>= 1) {
        s  += __shfl_xor(s, off);
        ss += __shfl_xor(ss, off);
    }
    float mu  = s * (1.f / 256.f);
    float var = ss * (1.f / 256.f) - mu * mu;
    float rstd = rsqrtf(var + 1e-5f);
    float4 gv = reinterpret_cast<const float4*>(g)[lane];
    float4 bv = reinterpret_cast<const float4*>(be)[lane];
    float4 o = {(x.x - mu) * rstd * gv.x + bv.x,
                (x.y - mu) * rstd * gv.y + bv.y,
                (x.z - mu) * rstd * gv.z + bv.z,
                (x.w - mu) * rstd * gv.w + bv.w};
    reinterpret_cast<float4*>(out + (size_t)row * 256)[lane] = o;
    float4 pv = reinterpret_cast<const float4*>(pos + (size_t)row * 256)[lane];
    ushort4 q4;
    q4.x = f32_to_bf16_bits(o.x + pv.x); q4.y = f32_to_bf16_bits(o.y + pv.y);
    q4.z = f32_to_bf16_bits(o.z + pv.z); q4.w = f32_to_bf16_bits(o.w + pv.w);
    *reinterpret_cast<ushort4*>(outb + (size_t)row * 256 + lane * 4) = q4;
}

// ============================================================================
// B-resident barrier-free GEMM (small GEMMs, bf16 A): C = A @ Bt^T + bias.
// CMODE: 0 = f32 out; 1 = bf16 out.
// ============================================================================
template<bool RELU, int CMODE, int BN, int K>
__global__ __launch_bounds__(256) void bgemm(const unsigned short* __restrict__ Ab,
                                             const unsigned short* __restrict__ Bt,
                                             const float* __restrict__ bias,
                                             float* __restrict__ Cf,
                                             unsigned short* __restrict__ Cb,
                                             int N)
{
    constexpr int NF   = BN / 16;
    constexpr int KF   = K / 32;
    constexpr int ROWB = K * 2;
    constexpr int FILL = BN * ROWB / 4096;

    __shared__ __align__(16) unsigned short sB[BN * K];

    const int tid = threadIdx.x;
    const int w = tid >> 6, l = tid & 63;
    const int g = l >> 4, lr = l & 15;
    const int n0 = blockIdx.x * BN;

    #pragma unroll
    for (int r = 0; r < FILL; r++) {
        int lin = (r * 256 + tid) * 16;
        int row = lin / ROWB;
        int kb  = (lin & (ROWB - 1)) ^ ((row & 7) << 4);
        async_copy16(Bt + (size_t)(n0 + row) * K + (kb >> 1), (char*)sB + lin);
    }
    asm volatile("s_waitcnt vmcnt(0)\n\ts_barrier" ::: "memory");

    float bz[NF];
    #pragma unroll
    for (int nf = 0; nf < NF; nf++) bz[nf] = bias[n0 + nf * 16 + lr];

    const int m0w = blockIdx.y * 64 + w * 16;
    const int arow = m0w + lr;

    f32x4 acc[NF];
    #pragma unroll
    for (int nf = 0; nf < NF; nf++)
        #pragma unroll
        for (int r = 0; r < 4; r++) acc[nf][r] = 0.f;

    #pragma unroll
    for (int kf = 0; kf < KF; kf++) {
        bf16x8 af = *reinterpret_cast<const bf16x8*>(Ab + (size_t)arow * K + kf * 32 + g * 8);
        #pragma unroll
        for (int nf = 0; nf < NF; nf++) {
            int brow = nf * 16 + lr;
            bf16x8 bf = *reinterpret_cast<const bf16x8*>(
                (const char*)sB + brow * ROWB + ((kf * 64 + g * 16) ^ ((brow & 7) << 4)));
            acc[nf] = __builtin_amdgcn_mfma_f32_16x16x32_bf16(af, bf, acc[nf], 0, 0, 0);
        }
    }

    #pragma unroll
    for (int nf = 0; nf < NF; nf++) {
        int col = n0 + nf * 16 + lr;
        #pragma unroll
        for (int rg = 0; rg < 4; rg++) {
            int row = m0w + g * 4 + rg;
            float v = acc[nf][rg] + bz[nf];
            if (RELU) v = fmaxf(v, 0.f);
            if constexpr (CMODE == 1)
                Cb[(size_t)row * N + col] = f32_to_bf16_bits(v);
            else
                Cf[(size_t)row * N + col] = v;
        }
    }
}

// ============================================================================
// LayerNorm: out = LN(a + b) * g + be. OM: 0 = f32 only; 1 = +bf16(out).
// ============================================================================
template<int OM>
__global__ __launch_bounds__(256) void ln_k(const float* __restrict__ a,
                                            const float* __restrict__ bsum,
                                            const float* __restrict__ g,
                                            const float* __restrict__ be,
                                            float* __restrict__ out,
                                            unsigned short* __restrict__ outb)
{
    const int wave = threadIdx.x >> 6, lane = threadIdx.x & 63;
    const int row = blockIdx.x * 4 + wave;
    float4 xa = reinterpret_cast<const float4*>(a + (size_t)row * 256)[lane];
    float4 xb = reinterpret_cast<const float4*>(bsum + (size_t)row * 256)[lane];
    float4 x = {xa.x + xb.x, xa.y + xb.y, xa.z + xb.z, xa.w + xb.w};
    float s  = x.x + x.y + x.z + x.w;
    float ss = x.x * x.x + x.y * x.y + x.z * x.z + x.w * x.w;
    #pragma unroll
    for (int off = 32; off > 0; off >>= 1) {
        s  += __shfl_xor(s, off);
        ss += __shfl_xor(ss, off);
    }
    float mu  = s * (1.f / 256.f);
    float var = ss * (1.f / 256.f) - mu * mu;
    float rstd = rsqrtf(var + 1e-5f);
    float4 gv = reinterpret_cast<const float4*>(g)[lane];
    float4 bv = reinterpret_cast<const float4*>(be)[lane];
    float4 o = {(x.x - mu) * rstd * gv.x + bv.x,
                (x.y - mu) * rstd * gv.y + bv.y,
                (x.z - mu) * rstd * gv.z + bv.z,
                (x.w - mu) * rstd * gv.w + bv.w};
    reinterpret_cast<float4*>(out + (size_t)row * 256)[lane] = o;
    if constexpr (OM == 1) {
        ushort4 q4;
        q4.x = f32_to_bf16_bits(o.x); q4.y = f32_to_bf16_bits(o.y);
        q4.z = f32_to_bf16_bits(o.z); q4.w = f32_to_bf16_bits(o.w);
        *reinterpret_cast<ushort4*>(outb + (size_t)row * 256 + lane * 4) = q4;
    }
}

// ============================================================================
// Deformable sampling on PROJECTED value (r14-verified): 2 tokens/block,
// 2 channels/thread.
// ============================================================================
__device__ inline unsigned int samp2(const unsigned short* __restrict__ v,
                                     int b, int st, int Wl, int Hl,
                                     int x, int y, int hc)
{
    bool valid = (x >= 0) & (x < Wl) & (y >= 0) & (y < Hl);
    int xc = min(max(x, 0), Wl - 1);
    int yc = min(max(y, 0), Hl - 1);
    size_t idx = ((size_t)(b * S_ + st + yc * Wl + xc)) * 256 + hc;
    unsigned int val = *reinterpret_cast<const unsigned int*>(v + idx);
    return valid ? val : 0u;
}

__global__ __launch_bounds__(256) void deform_k(const float* __restrict__ rp,
                                                const float* __restrict__ oa,
                                                const unsigned short* __restrict__ value,
                                                unsigned short* __restrict__ ca)
{
    const int tk = threadIdx.x >> 7;
    const int tok = blockIdx.x * 2 + tk;
    const int b = tok / NQ_;
    const int h = (threadIdx.x >> 4) & 7;
    const int cp = threadIdx.x & 15;
    const int hc = h * 32 + cp * 2;

    const float* awp = oa + (size_t)tok * 384 + 256 + h * 16;
    float w[16];
    float mx = -1e30f;
    #pragma unroll
    for (int i = 0; i < 16; i++) { w[i] = awp[i]; mx = fmaxf(mx, w[i]); }
    float sum = 0.f;
    #pragma unroll
    for (int i = 0; i < 16; i++) { w[i] = __expf(w[i] - mx); sum += w[i]; }
    const float inv = 1.f / sum;

    const float* rpp  = rp + (size_t)tok * (L_ * 4);
    const float* offp = oa + (size_t)tok * 384 + h * 32;

    const int lvlW[4] = {128, 64, 32, 16};
    const int lvlS[4] = {0, 16384, 20480, 21504};

    float acc0 = 0.f, acc1 = 0.f;
    #pragma unroll
    for (int l = 0; l < 4; l++) {
        const int Wl = lvlW[l], Hl = lvlW[l], st = lvlS[l];
        const float cx = rpp[l * 4 + 0], cy = rpp[l * 4 + 1];
        const float cw = rpp[l * 4 + 2], chh = rpp[l * 4 + 3];
        #pragma unroll
        for (int p = 0; p < 4; p++) {
            float ox = offp[l * 8 + p * 2 + 0];
            float oy = offp[l * 8 + p * 2 + 1];
            float lx = (cx + ox * 0.25f * cw * 0.5f) * Wl - 0.5f;
            float ly = (cy + oy * 0.25f * chh * 0.5f) * Hl - 0.5f;
            float x0f = floorf(lx), y0f = floorf(ly);
            float tx = lx - x0f, ty = ly - y0f;
            int x0 = (int)x0f, y0 = (int)y0f;
            unsigned int u00 = samp2(value, b, st, Wl, Hl, x0,     y0,     hc);
            unsigned int u01 = samp2(value, b, st, Wl, Hl, x0 + 1, y0,     hc);
            unsigned int u10 = samp2(value, b, st, Wl, Hl, x0,     y0 + 1, hc);
            unsigned int u11 = samp2(value, b, st, Wl, Hl, x0 + 1, y0 + 1, hc);
            float w00 = (1.f - tx) * (1.f - ty), w01 = tx * (1.f - ty);
            float w10 = (1.f - tx) * ty,         w11 = tx * ty;
            float g0 = bf16_bits_to_f32((unsigned short)u00) * w00
                     + bf16_bits_to_f32((unsigned short)u01) * w01
                     + bf16_bits_to_f32((unsigned short)u10) * w10
                     + bf16_bits_to_f32((unsigned short)u11) * w11;
            float g1 = bf16_bits_to_f32((unsigned short)(u00 >> 16)) * w00
                     + bf16_bits_to_f32((unsigned short)(u01 >> 16)) * w01
                     + bf16_bits_to_f32((unsigned short)(u10 >> 16)) * w10
                     + bf16_bits_to_f32((unsigned short)(u11 >> 16)) * w11;
            float wa = w[l * 4 + p] * inv;
            acc0 += wa * g0;
            acc1 += wa * g1;
        }
    }
    unsigned int packed = ((unsigned)f32_to_bf16_bits(acc0)) | (((unsigned)f32_to_bf16_bits(acc1)) << 16);
    *reinterpret_cast<unsigned int*>(ca + (size_t)tok * 256 + hc) = packed;
}

// ============================================================================
extern "C" void kernel_launch(void* const* d_in, const int* in_sizes, int n_in,
                              void* d_out, int out_size, void* d_ws, size_t ws_size,
                              hipStream_t stream)
{
    const float* query      = (const float*)d_in[0];
    const float* query_pos  = (const float*)d_in[1];
    const float* ref_pts    = (const float*)d_in[2];
    const float* input_flat = (const float*)d_in[3];
    const float* Wq = (const float*)d_in[6];  const float* bq = (const float*)d_in[7];
    const float* Wk = (const float*)d_in[8];  const float* bk = (const float*)d_in[9];
    const float* Wv = (const float*)d_in[10]; const float* bv = (const float*)d_in[11];
    const float* Wo = (const float*)d_in[12]; const float* bo = (const float*)d_in[13];
    const float* ln1g = (const float*)d_in[14]; const float* ln1b = (const float*)d_in[15];
    const float* W_off = (const float*)d_in[16]; const float* b_off = (const float*)d_in[17];
    const float* W_attn = (const float*)d_in[18]; const float* b_attn = (const float*)d_in[19];
    const float* W_val = (const float*)d_in[20]; const float* b_val = (const float*)d_in[21];
    const float* W_cout = (const float*)d_in[22]; const float* b_cout = (const float*)d_in[23];
    const float* ln2g = (const float*)d_in[24]; const float* ln2b = (const float*)d_in[25];
    const float* W1 = (const float*)d_in[26]; const float* b1 = (const float*)d_in[27];
    const float* W2 = (const float*)d_in[28]; const float* b2 = (const float*)d_in[29];
    const float* ln3g = (const float*)d_in[30]; const float* ln3b = (const float*)d_in[31];
    float* out = (float*)d_out;

    // ---- workspace arena ----
    char* base = (char*)d_ws;
    size_t off = 0;
    auto alloc = [&](size_t bytes) { void* p = base + off; off += (bytes + 255) & ~(size_t)255; return p; };
    unsigned short* value_bf = (unsigned short*)alloc((size_t)B_ * S_ * 256 * 2);   // 89.1 MB
    unsigned short* qk_bf = (unsigned short*)alloc((size_t)NTOK * 1024 * 2);        // qk ∪ h_bf
    unsigned short* h_bf = qk_bf;
    unsigned short* vt = (unsigned short*)alloc((size_t)B_ * 256 * 1024 * 2);       // 4.2 MB
    float* oa_buf = (float*)alloc((size_t)NTOK * 384 * 4);
    float* tmp0   = (float*)alloc((size_t)NTOK * 256 * 4);
    float* x1     = (float*)alloc((size_t)NTOK * 256 * 4);
    float* x2     = (float*)alloc((size_t)NTOK * 256 * 4);
    unsigned short* sc_bf  = (unsigned short*)alloc((size_t)NTOK * 256 * 2);
    unsigned short* q_bf   = (unsigned short*)alloc((size_t)NTOK * 256 * 2);
    unsigned short* qp_bf  = (unsigned short*)alloc((size_t)NTOK * 256 * 2);
    unsigned short* x1p_bf = (unsigned short*)alloc((size_t)NTOK * 256 * 2);
    unsigned short* x2_bf  = (unsigned short*)alloc((size_t)NTOK * 256 * 2);
    unsigned short* wqkv  = (unsigned short*)alloc(768 * 256 * 2);
    unsigned short* wo    = (unsigned short*)alloc(256 * 256 * 2);
    unsigned short* woa   = (unsigned short*)alloc(384 * 256 * 2);
    unsigned short* wval  = (unsigned short*)alloc(256 * 256 * 2);
    unsigned short* wcout = (unsigned short*)alloc(256 * 256 * 2);
    unsigned short* w1t   = (unsigned short*)alloc(1024 * 256 * 2);
    unsigned short* w2t   = (unsigned short*)alloc(256 * 1024 * 2);
    float* qkvbias = (float*)alloc(768 * 4);
    float* oabias  = (float*)alloc(384 * 4);

    dim3 blk(256);

    // ---- fused prep ----
    PrepArgs P;
    P.wsrc[0] = Wq;    P.wdst[0] = wqkv;              P.wK[0] = 256;  P.wN[0] = 256;
    P.wsrc[1] = Wk;    P.wdst[1] = wqkv + 256 * 256;  P.wK[1] = 256;  P.wN[1] = 256;
    P.wsrc[2] = Wv;    P.wdst[2] = wqkv + 512 * 256;  P.wK[2] = 256;  P.wN[2] = 256;
    P.wsrc[3] = Wo;    P.wdst[3] = wo;                P.wK[3] = 256;  P.wN[3] = 256;
    P.wsrc[4] = W_off; P.wdst[4] = woa;               P.wK[4] = 256;  P.wN[4] = 256;
    P.wsrc[5] = W_attn;P.wdst[5] = woa + 256 * 256;   P.wK[5] = 256;  P.wN[5] = 128;
    P.wsrc[6] = W_val; P.wdst[6] = wval;              P.wK[6] = 256;  P.wN[6] = 256;
    P.wsrc[7] = W_cout;P.wdst[7] = wcout;             P.wK[7] = 256;  P.wN[7] = 256;
    P.wsrc[8] = W1;    P.wdst[8] = w1t;               P.wK[8] = 256;  P.wN[8] = 1024;
    P.wsrc[9] = W2;    P.wdst[9] = w2t;               P.wK[9] = 1024; P.wN[9] = 256;
    P.bq = bq; P.bk = bk; P.bv = bv; P.boff = b_off; P.battn = b_attn;
    P.qkvb = qkvbias; P.oab = oabias;
    P.query = query; P.qpos = query_pos; P.q_bf = q_bf; P.qp_bf = qp_bf;
    prep_k<<<891, blk, 0, stream>>>(P);

    VArgs V;
    V.Af = input_flat; V.Bt = wval; V.bias = b_val; V.Cb = value_bf;

    // ---- self-attention block, with vgemmF slices co-scheduled ----
    qkvF <<<1500 + 654,  blk, 0, stream>>>(qp_bf, q_bf, wqkv, qkvbias, qk_bf, vt, V);
    fattnF<<<1024 + 1046, blk, 0, stream>>>(qk_bf, vt, sc_bf, V);
    woF  <<<500 + 523,   blk, 0, stream>>>(sc_bf, wo, bo, tmp0, V);
    ln1F <<<2000 + 497,  blk, 0, stream>>>(query, tmp0, query_pos, ln1g, ln1b, x1, x1p_bf, V);

    // ---- deformable cross-attention ----
    bgemm<false, 0,  64, 256><<<dim3(6, 125), blk, 0, stream>>>(x1p_bf, woa, oabias, oa_buf, nullptr, 384);
    deform_k<<<NTOK / 2, blk, 0, stream>>>(ref_pts, oa_buf, value_bf, sc_bf);
    bgemm<false, 0,  64, 256><<<dim3(4, 125), blk, 0, stream>>>(sc_bf, wcout, b_cout, tmp0, nullptr, 256);
    ln_k<1><<<NTOK / 4, blk, 0, stream>>>(x1, tmp0, ln2g, ln2b, x2, x2_bf);

    // ---- FFN ----
    bgemm<true,  1,  64, 256><<<dim3(16, 125), blk, 0, stream>>>(x2_bf, w1t, b1, nullptr, h_bf, 1024);
    bgemm<false, 0,  32, 1024><<<dim3(8, 125), blk, 0, stream>>>(h_bf, w2t, b2, tmp0, nullptr, 256);
    ln_k<0><<<NTOK / 4, blk, 0, stream>>>(x2, tmp0, ln3g, ln3b, out, nullptr);
}

// Round 17
// 319.478 us; speedup vs baseline: 1.0569x; 1.0569x over previous
//
#include <hip/hip_runtime.h>
#include <hip/hip_bf16.h>

#define B_   8
#define NQ_  1000
#define D_   256
#define NH_  8
#define L_   4
#define P_   4
#define DFF_ 1024
#define HD_  32
#define S_   21760
#define NTOK (B_*NQ_)

typedef short  bf16x8 __attribute__((ext_vector_type(8)));
typedef float  f32x4  __attribute__((ext_vector_type(4)));

#define WAITBAR(N) asm volatile("s_waitcnt vmcnt(" #N ") lgkmcnt(0)\n\ts_barrier" ::: "memory")
#define ENDBAR()   asm volatile("s_barrier" ::: "memory")

__device__ inline unsigned short f32_to_bf16_bits(float f) {
    unsigned int u = __float_as_uint(f);
    unsigned int rounding = 0x7FFFu + ((u >> 16) & 1u);
    u += rounding;
    return (unsigned short)(u >> 16);
}
__device__ inline float bf16_bits_to_f32(unsigned short b) {
    return __uint_as_float(((unsigned int)b) << 16);
}
// {bf16_trunc(f1)<<16 | bf16_trunc(f0)} in ONE v_perm_b32
__device__ inline unsigned int pack_trunc(float f0, float f1) {
    return __builtin_amdgcn_perm(__float_as_uint(f1), __float_as_uint(f0), 0x07060302u);
}
__device__ inline void async_copy16(const void* g, void* l) {
    __builtin_amdgcn_global_load_lds((const __attribute__((address_space(1))) unsigned int*)g,
                                     (__attribute__((address_space(3))) unsigned int*)l, 16, 0, 0);
}

// ============================================================================
// Value-projection GEMM body (r14-verified vgemmF), callable from fused
// kernels. 48KB smem. vbid in [0,2720): n0=(vbid&1)*128, m0=(vbid>>1)*128.
// ============================================================================
struct VArgs {
    const float* Af;
    const unsigned short* Bt;
    const float* bias;
    unsigned short* Cb;
};

__device__ inline void vgemm_body(char* smem, int vbid, const VArgs V)
{
    constexpr int K = 256;
    constexpr int N = 256;
    float* sA0 = reinterpret_cast<float*>(smem);                           // 2 x 16KB
    unsigned short* sB0 = reinterpret_cast<unsigned short*>(smem + 32768); // 2 x 8KB

    const int tid = threadIdx.x;
    const int w = tid >> 6, l = tid & 63;
    const int n0 = (vbid & 1) * 128, m0 = (vbid >> 1) * 128;
    const int wr = w >> 1, wc = w & 1;
    const int lq = l & 15, g = l >> 4;

    f32x4 acc[4][4];
    #pragma unroll
    for (int i = 0; i < 4; i++)
        #pragma unroll
        for (int j = 0; j < 4; j++)
            #pragma unroll
            for (int r = 0; r < 4; r++) acc[i][j][r] = 0.f;

    auto issueA = [&](int t, int buf) {
        #pragma unroll
        for (int r = 0; r < 4; r++) {
            int lin = (r * 256 + tid) * 16;
            int row = lin >> 7;
            int kb  = (lin & 127) ^ ((row & 7) << 4);
            async_copy16(V.Af + (size_t)(m0 + row) * K + t * 32 + (kb >> 2),
                         (char*)(sA0 + (size_t)buf * 4096) + lin);
        }
    };
    auto issueB = [&](int t, int buf) {
        #pragma unroll
        for (int r = 0; r < 2; r++) {
            int lin = (r * 256 + tid) * 16;
            int row = lin >> 6;
            int kb  = (lin & 63) ^ ((row & 3) << 4);
            async_copy16(V.Bt + (size_t)(n0 + row) * K + t * 32 + (kb >> 1),
                         (char*)(sB0 + (size_t)buf * 4096) + lin);
        }
    };

    issueA(0, 0);
    issueB(0, 0);

    for (int t = 0; t < 8; t++) {
        const int cur = t & 1;
        if (t + 1 < 8) {
            issueA(t + 1, cur ^ 1);
            issueB(t + 1, cur ^ 1);
            WAITBAR(6);
        } else {
            WAITBAR(0);
        }

        const float* sA = sA0 + (size_t)cur * 4096;
        const unsigned short* sB = sB0 + (size_t)cur * 4096;
        bf16x8 afr[4], bfr[4];
        #pragma unroll
        for (int mi = 0; mi < 4; mi++) {
            int row = wr * 64 + mi * 16 + lq;
            int sw  = (row & 7) << 4;
            int p0  = (g * 32) ^ sw;
            const char* p = (const char*)sA + row * 128;
            float4 a0 = *reinterpret_cast<const float4*>(p + p0);
            float4 a1 = *reinterpret_cast<const float4*>(p + (p0 ^ 16));
            uint4 u;
            u.x = pack_trunc(a0.x, a0.y);
            u.y = pack_trunc(a0.z, a0.w);
            u.z = pack_trunc(a1.x, a1.y);
            u.w = pack_trunc(a1.z, a1.w);
            afr[mi] = *reinterpret_cast<bf16x8*>(&u);
        }
        #pragma unroll
        for (int ni = 0; ni < 4; ni++) {
            int row = wc * 64 + ni * 16 + lq;
            int off = (g * 16) ^ ((row & 3) << 4);
            bfr[ni] = *reinterpret_cast<const bf16x8*>((const char*)sB + row * 64 + off);
        }
        #pragma unroll
        for (int mi = 0; mi < 4; mi++)
            #pragma unroll
            for (int ni = 0; ni < 4; ni++)
                acc[mi][ni] = __builtin_amdgcn_mfma_f32_16x16x32_bf16(
                    afr[mi], bfr[ni], acc[mi][ni], 0, 0, 0);
        ENDBAR();
    }

    #pragma unroll
    for (int mi = 0; mi < 4; mi++) {
        #pragma unroll
        for (int ni = 0; ni < 4; ni++) {
            int col = n0 + wc * 64 + ni * 16 + lq;
            float bz = V.bias[col];
            #pragma unroll
            for (int rg = 0; rg < 4; rg++) {
                int row = m0 + wr * 64 + mi * 16 + g * 4 + rg;
                V.Cb[(size_t)row * N + col] = f32_to_bf16_bits(acc[mi][ni][rg] + bz);
            }
        }
    }
}

// Standalone wrapper for the remaining vgemm blocks.
__global__ __launch_bounds__(256) void vgemmS(VArgs V, int base)
{
    __shared__ __align__(16) char smem[49152];
    vgemm_body(smem, base + blockIdx.x, V);
}

// ============================================================================
// Fused prep (r14): weights 0..639, bias 640, q/qp 641..890.
// ============================================================================
struct PrepArgs {
    const float* wsrc[10];
    unsigned short* wdst[10];
    int wK[10], wN[10];
    const float* bq; const float* bk; const float* bv; const float* boff; const float* battn;
    float* qkvb; float* oab;
    const float* query; const float* qpos;
    unsigned short* q_bf; unsigned short* qp_bf;
};
__global__ __launch_bounds__(256) void prep_k(PrepArgs P)
{
    const int bid = blockIdx.x, tid = threadIdx.x;
    if (bid < 640) {
        const int job = bid >> 6, tile = bid & 63;
        const int K = P.wK[job], N = P.wN[job];
        const int tilesN = N >> 6;
        if (tile >= (K >> 6) * tilesN) return;
        const int kt = tile / tilesN, nt = tile - kt * tilesN;
        const int k0 = kt * 64, n0 = nt * 64;
        __shared__ unsigned short t_[64][65];
        const float* src = P.wsrc[job];
        unsigned short* dst = P.wdst[job];
        const int cc = tid & 63, rr = tid >> 6;
        #pragma unroll
        for (int i = 0; i < 16; i++) {
            int k = i * 4 + rr;
            t_[k][cc] = f32_to_bf16_bits(src[(size_t)(k0 + k) * N + n0 + cc]);
        }
        __syncthreads();
        #pragma unroll
        for (int i = 0; i < 16; i++) {
            int n = i * 4 + rr;
            dst[(size_t)(n0 + n) * K + k0 + cc] = t_[cc][n];
        }
    } else if (bid == 640) {
        P.qkvb[tid]       = P.bq[tid];
        P.qkvb[256 + tid] = P.bk[tid];
        P.qkvb[512 + tid] = P.bv[tid];
        P.oab[tid]        = P.boff[tid];
        if (tid < 128) P.oab[256 + tid] = P.battn[tid];
    } else {
        const int base = (bid - 641) * 1024 + tid;
        float4 fq[4][2], fp[4][2];
        #pragma unroll
        for (int i = 0; i < 4; i++) {
            const float* q = P.query + (size_t)(base + i * 256) * 8;
            const float* p = P.qpos  + (size_t)(base + i * 256) * 8;
            fq[i][0] = *reinterpret_cast<const float4*>(q);
            fq[i][1] = *reinterpret_cast<const float4*>(q + 4);
            fp[i][0] = *reinterpret_cast<const float4*>(p);
            fp[i][1] = *reinterpret_cast<const float4*>(p + 4);
        }
        #pragma unroll
        for (int i = 0; i < 4; i++) {
            uint4 tq, tp;
            tq.x = pack_trunc(fq[i][0].x, fq[i][0].y);
            tq.y = pack_trunc(fq[i][0].z, fq[i][0].w);
            tq.z = pack_trunc(fq[i][1].x, fq[i][1].y);
            tq.w = pack_trunc(fq[i][1].z, fq[i][1].w);
            tp.x = pack_trunc(fq[i][0].x + fp[i][0].x, fq[i][0].y + fp[i][0].y);
            tp.y = pack_trunc(fq[i][0].z + fp[i][0].z, fq[i][0].w + fp[i][0].w);
            tp.z = pack_trunc(fq[i][1].x + fp[i][1].x, fq[i][1].y + fp[i][1].y);
            tp.w = pack_trunc(fq[i][1].z + fp[i][1].z, fq[i][1].w + fp[i][1].w);
            *reinterpret_cast<uint4*>(P.q_bf  + (size_t)(base + i * 256) * 8) = tq;
            *reinterpret_cast<uint4*>(P.qp_bf + (size_t)(base + i * 256) * 8) = tp;
        }
    }
}

// ============================================================================
// FUSED: q/k/v projection (blocks 0..1499, low-VGPR) + vgemm slice [0,500).
// ============================================================================
__global__ __launch_bounds__(256) void qkvF(const unsigned short* __restrict__ qp_bf,
                                            const unsigned short* __restrict__ q_bf,
                                            const unsigned short* __restrict__ Bt,
                                            const float* __restrict__ bias,
                                            unsigned short* __restrict__ qk_out,
                                            unsigned short* __restrict__ vt_out,
                                            VArgs V)
{
    __shared__ __align__(16) char smem[49152];
    const int bid = blockIdx.x;
    if (bid >= 1500) { vgemm_body(smem, bid - 1500, V); return; }

    constexpr int K = 256;
    unsigned short* sB = reinterpret_cast<unsigned short*>(smem);  // 32KB

    const int tid = threadIdx.x;
    const int w = tid >> 6, l = tid & 63;
    const int g = l >> 4, lr = l & 15;
    const int n0 = (bid % 12) * 64;
    const int my = bid / 12;
    const bool isV = (n0 >= 512);
    const unsigned short* Ab = isV ? q_bf : qp_bf;

    #pragma unroll
    for (int r = 0; r < 8; r++) {
        int lin = (r * 256 + tid) * 16;
        int row = lin >> 9;
        int kb  = (lin & 511) ^ ((row & 7) << 4);
        async_copy16(Bt + (size_t)(n0 + row) * K + (kb >> 1), (char*)sB + lin);
    }
    asm volatile("s_waitcnt vmcnt(0)\n\ts_barrier" ::: "memory");

    float bz[4];
    #pragma unroll
    for (int nf = 0; nf < 4; nf++) bz[nf] = bias[n0 + nf * 16 + lr];

    const int m0w = my * 64 + w * 16;
    const int arow = m0w + lr;

    f32x4 acc[4];
    #pragma unroll
    for (int nf = 0; nf < 4; nf++)
        #pragma unroll
        for (int r = 0; r < 4; r++) acc[nf][r] = 0.f;

    #pragma unroll
    for (int kf = 0; kf < 8; kf++) {
        bf16x8 af = *reinterpret_cast<const bf16x8*>(Ab + (size_t)arow * K + kf * 32 + g * 8);
        #pragma unroll
        for (int nf = 0; nf < 4; nf++) {
            int brow = nf * 16 + lr;
            bf16x8 bf = *reinterpret_cast<const bf16x8*>(
                (const char*)sB + brow * 512 + ((kf * 64 + g * 16) ^ ((brow & 7) << 4)));
            acc[nf] = __builtin_amdgcn_mfma_f32_16x16x32_bf16(af, bf, acc[nf], 0, 0, 0);
        }
    }

    if (!isV) {
        #pragma unroll
        for (int nf = 0; nf < 4; nf++) {
            int col = n0 + nf * 16 + lr;
            #pragma unroll
            for (int rg = 0; rg < 4; rg++) {
                int row = m0w + g * 4 + rg;
                qk_out[(size_t)row * 512 + col] = f32_to_bf16_bits(acc[nf][rg] + bz[nf]);
            }
        }
    } else {
        #pragma unroll
        for (int nf = 0; nf < 4; nf++) {
            int col = n0 - 512 + nf * 16 + lr;
            int row0 = m0w + g * 4;
            int bb = row0 / 1000;
            int key = row0 - bb * 1000;
            ushort4 q4;
            q4.x = f32_to_bf16_bits(acc[nf][0] + bz[nf]);
            q4.y = f32_to_bf16_bits(acc[nf][1] + bz[nf]);
            q4.z = f32_to_bf16_bits(acc[nf][2] + bz[nf]);
            q4.w = f32_to_bf16_bits(acc[nf][3] + bz[nf]);
            *reinterpret_cast<ushort4*>(vt_out + (size_t)bb * 262144 + (size_t)col * 1024 + key) = q4;
        }
    }
}

// ============================================================================
// Standalone MFMA flash self-attention (r14-verified; high VGPR, NOT fused).
// ============================================================================
__global__ __launch_bounds__(256) void fattn_k(const unsigned short* __restrict__ qk,
                                               const unsigned short* __restrict__ vt,
                                               unsigned short* __restrict__ sa)
{
    const int b = blockIdx.z, h = blockIdx.y;
    const int tid = threadIdx.x;
    const int w = tid >> 6, l = tid & 63;
    const int lq = l & 15, g = l >> 4;
    const int q0 = blockIdx.x * 64 + w * 16;

    __shared__ __align__(16) unsigned short Ks[2][128 * 32];
    __shared__ __align__(16) unsigned short Vs[2][32 * 128];
    __shared__ __align__(16) unsigned short Ps[4][16 * 128];

    int qrow = q0 + lq; if (qrow > NQ_ - 1) qrow = NQ_ - 1;
    const bf16x8 qfrag = *reinterpret_cast<const bf16x8*>(
        qk + ((size_t)(b * NQ_ + qrow)) * 512 + h * 32 + g * 8);

    f32x4 O0 = {0.f, 0.f, 0.f, 0.f}, O1 = {0.f, 0.f, 0.f, 0.f};
    float m = -1e30f, lsum = 0.f;
    const float scale = 0.17677669529663687f;

    const size_t kbase = (size_t)b * (NQ_ * 512) + 256 + h * 32;
    const size_t vbase = (size_t)b * 262144 + (size_t)(h * 32) * 1024;
    const int swz = (lq & 7) << 4;

    auto issueKV = [&](int kt, int buf) {
        #pragma unroll
        for (int r = 0; r < 2; r++) {
            int lin = (r * 256 + tid) * 16;
            int krow = lin >> 6;
            int kb = (lin & 63) ^ ((krow & 7) << 4);
            async_copy16(qk + kbase + (size_t)(kt * 128 + krow) * 512 + (kb >> 1),
                         (char*)Ks[buf] + lin);
            int d = lin >> 8;
            int vb = (lin & 255) ^ ((d & 7) << 4);
            async_copy16(vt + vbase + (size_t)d * 1024 + kt * 128 + (vb >> 1),
                         (char*)Vs[buf] + lin);
        }
    };

    issueKV(0, 0);

    for (int kt = 0; kt < 8; kt++) {
        const int k0 = kt * 128;
        const int cur = kt & 1;
        asm volatile("s_waitcnt vmcnt(0) lgkmcnt(0)\n\ts_barrier" ::: "memory");
        if (kt < 7) issueKV(kt + 1, cur ^ 1);

        const unsigned short* Kc = Ks[cur];
        const unsigned short* Vc = Vs[cur];

        float t[8][4];
        float tmax = -1e30f;
        const bool tail = (k0 + 128 > NQ_);
        #pragma unroll
        for (int ni = 0; ni < 8; ni++) {
            int row = ni * 16 + lq;
            bf16x8 kf = *reinterpret_cast<const bf16x8*>(
                (const char*)Kc + row * 64 + ((g * 16) ^ swz));
            f32x4 st = __builtin_amdgcn_mfma_f32_16x16x32_bf16(
                kf, qfrag, (f32x4){0.f, 0.f, 0.f, 0.f}, 0, 0, 0);
            #pragma unroll
            for (int rg = 0; rg < 4; rg++) {
                float tv = st[rg] * scale;
                if (tail) {
                    int key = k0 + ni * 16 + g * 4 + rg;
                    tv = (key < NQ_) ? tv : -1e30f;
                }
                t[ni][rg] = tv;
                tmax = fmaxf(tmax, tv);
            }
        }
        tmax = fmaxf(tmax, __shfl_xor(tmax, 16));
        tmax = fmaxf(tmax, __shfl_xor(tmax, 32));
        float mnew = fmaxf(m, tmax);
        float corr = __expf(m - mnew);
        m = mnew;

        float rs = 0.f;
        unsigned int pk[8][2];
        #pragma unroll
        for (int ni = 0; ni < 8; ni++) {
            float p0 = __expf(t[ni][0] - mnew);
            float p1 = __expf(t[ni][1] - mnew);
            float p2 = __expf(t[ni][2] - mnew);
            float p3 = __expf(t[ni][3] - mnew);
            rs += (p0 + p1) + (p2 + p3);
            pk[ni][0] = ((unsigned)f32_to_bf16_bits(p0)) | (((unsigned)f32_to_bf16_bits(p1)) << 16);
            pk[ni][1] = ((unsigned)f32_to_bf16_bits(p2)) | (((unsigned)f32_to_bf16_bits(p3)) << 16);
        }
        rs += __shfl_xor(rs, 16);
        rs += __shfl_xor(rs, 32);
        lsum = lsum * corr + rs;

        float c0 = __shfl(corr, g * 4 + 0);
        float c1 = __shfl(corr, g * 4 + 1);
        float c2 = __shfl(corr, g * 4 + 2);
        float c3 = __shfl(corr, g * 4 + 3);
        O0[0] *= c0; O0[1] *= c1; O0[2] *= c2; O0[3] *= c3;
        O1[0] *= c0; O1[1] *= c1; O1[2] *= c2; O1[3] *= c3;

        unsigned short* Pw = Ps[w];
        #pragma unroll
        for (int ni = 0; ni < 8; ni++) {
            int byteoff = lq * 256 + ((ni * 32 + g * 8) ^ swz);
            *reinterpret_cast<uint2*>((char*)Pw + byteoff) = make_uint2(pk[ni][0], pk[ni][1]);
        }

        #pragma unroll
        for (int c = 0; c < 4; c++) {
            int rb = (c * 64 + g * 16) ^ swz;
            bf16x8 pa = *reinterpret_cast<const bf16x8*>((const char*)Pw + lq * 256 + rb);
            bf16x8 v0 = *reinterpret_cast<const bf16x8*>((const char*)Vc + lq * 256 + rb);
            bf16x8 v1 = *reinterpret_cast<const bf16x8*>((const char*)Vc + (16 + lq) * 256 + rb);
            O0 = __builtin_amdgcn_mfma_f32_16x16x32_bf16(pa, v0, O0, 0, 0, 0);
            O1 = __builtin_amdgcn_mfma_f32_16x16x32_bf16(pa, v1, O1, 0, 0, 0);
        }
    }

    float linv = 1.f / lsum;
    float i0 = __shfl(linv, g * 4 + 0);
    float i1 = __shfl(linv, g * 4 + 1);
    float i2 = __shfl(linv, g * 4 + 2);
    float i3 = __shfl(linv, g * 4 + 3);
    float iv[4] = {i0, i1, i2, i3};
    #pragma unroll
    for (int rg = 0; rg < 4; rg++) {
        int qg = q0 + g * 4 + rg;
        if (qg < NQ_) {
            size_t obase = ((size_t)(b * NQ_ + qg)) * 256 + h * 32;
            sa[obase + lq]      = f32_to_bf16_bits(O0[rg] * iv[rg]);
            sa[obase + 16 + lq] = f32_to_bf16_bits(O1[rg] * iv[rg]);
        }
    }
}

// ============================================================================
// FUSED: sa @ Wo GEMM (blocks 0..499) + vgemm slice [500,750).
// ============================================================================
__global__ __launch_bounds__(256) void woF(const unsigned short* __restrict__ Ab,
                                           const unsigned short* __restrict__ Bt,
                                           const float* __restrict__ bias,
                                           float* __restrict__ Cf,
                                           VArgs V)
{
    __shared__ __align__(16) char smem[49152];
    const int bid = blockIdx.x;
    if (bid >= 500) { vgemm_body(smem, 500 + bid - 500 - 0 + 0, V); return; }  // slice base applied below
    // NOTE: slice base folded in launcher via grid split: bid-500 + 500 = bid.
    // (kept simple: vgemm_body(smem, bid, V) would be wrong; see launcher)

    constexpr int K = 256;
    unsigned short* sB = reinterpret_cast<unsigned short*>(smem);  // 32KB

    const int tid = threadIdx.x;
    const int w = tid >> 6, l = tid & 63;
    const int g = l >> 4, lr = l & 15;
    const int n0 = (bid & 3) * 64;
    const int my = bid >> 2;

    #pragma unroll
    for (int r = 0; r < 8; r++) {
        int lin = (r * 256 + tid) * 16;
        int row = lin >> 9;
        int kb  = (lin & 511) ^ ((row & 7) << 4);
        async_copy16(Bt + (size_t)(n0 + row) * K + (kb >> 1), (char*)sB + lin);
    }
    asm volatile("s_waitcnt vmcnt(0)\n\ts_barrier" ::: "memory");

    float bz[4];
    #pragma unroll
    for (int nf = 0; nf < 4; nf++) bz[nf] = bias[n0 + nf * 16 + lr];

    const int m0w = my * 64 + w * 16;
    const int arow = m0w + lr;

    f32x4 acc[4];
    #pragma unroll
    for (int nf = 0; nf < 4; nf++)
        #pragma unroll
        for (int r = 0; r < 4; r++) acc[nf][r] = 0.f;

    #pragma unroll
    for (int kf = 0; kf < 8; kf++) {
        bf16x8 af = *reinterpret_cast<const bf16x8*>(Ab + (size_t)arow * K + kf * 32 + g * 8);
        #pragma unroll
        for (int nf = 0; nf < 4; nf++) {
            int brow = nf * 16 + lr;
            bf16x8 bf = *reinterpret_cast<const bf16x8*>(
                (const char*)sB + brow * 512 + ((kf * 64 + g * 16) ^ ((brow & 7) << 4)));
            acc[nf] = __builtin_amdgcn_mfma_f32_16x16x32_bf16(af, bf, acc[nf], 0, 0, 0);
        }
    }

    #pragma unroll
    for (int nf = 0; nf < 4; nf++) {
        int col = n0 + nf * 16 + lr;
        #pragma unroll
        for (int rg = 0; rg < 4; rg++) {
            int row = m0w + g * 4 + rg;
            Cf[(size_t)row * 256 + col] = acc[nf][rg] + bz[nf];
        }
    }
}

// ============================================================================
// FUSED: woa GEMM, N=384 (blocks 0..749) + vgemm slice via launcher base.
// ============================================================================
__global__ __launch_bounds__(256) void woaF(const unsigned short* __restrict__ Ab,
                                            const unsigned short* __restrict__ Bt,
                                            const float* __restrict__ bias,
                                            float* __restrict__ Cf,
                                            VArgs V, int vbase)
{
    __shared__ __align__(16) char smem[49152];
    const int bid = blockIdx.x;
    if (bid >= 750) { vgemm_body(smem, vbase + bid - 750, V); return; }

    constexpr int K = 256;
    unsigned short* sB = reinterpret_cast<unsigned short*>(smem);  // 32KB

    const int tid = threadIdx.x;
    const int w = tid >> 6, l = tid & 63;
    const int g = l >> 4, lr = l & 15;
    const int n0 = (bid % 6) * 64;
    const int my = bid / 6;

    #pragma unroll
    for (int r = 0; r < 8; r++) {
        int lin = (r * 256 + tid) * 16;
        int row = lin >> 9;
        int kb  = (lin & 511) ^ ((row & 7) << 4);
        async_copy16(Bt + (size_t)(n0 + row) * K + (kb >> 1), (char*)sB + lin);
    }
    asm volatile("s_waitcnt vmcnt(0)\n\ts_barrier" ::: "memory");

    float bz[4];
    #pragma unroll
    for (int nf = 0; nf < 4; nf++) bz[nf] = bias[n0 + nf * 16 + lr];

    const int m0w = my * 64 + w * 16;
    const int arow = m0w + lr;

    f32x4 acc[4];
    #pragma unroll
    for (int nf = 0; nf < 4; nf++)
        #pragma unroll
        for (int r = 0; r < 4; r++) acc[nf][r] = 0.f;

    #pragma unroll
    for (int kf = 0; kf < 8; kf++) {
        bf16x8 af = *reinterpret_cast<const bf16x8*>(Ab + (size_t)arow * K + kf * 32 + g * 8);
        #pragma unroll
        for (int nf = 0; nf < 4; nf++) {
            int brow = nf * 16 + lr;
            bf16x8 bf = *reinterpret_cast<const bf16x8*>(
                (const char*)sB + brow * 512 + ((kf * 64 + g * 16) ^ ((brow & 7) << 4)));
            acc[nf] = __builtin_amdgcn_mfma_f32_16x16x32_bf16(af, bf, acc[nf], 0, 0, 0);
        }
    }

    #pragma unroll
    for (int nf = 0; nf < 4; nf++) {
        int col = n0 + nf * 16 + lr;
        #pragma unroll
        for (int rg = 0; rg < 4; rg++) {
            int row = m0w + g * 4 + rg;
            Cf[(size_t)row * 384 + col] = acc[nf][rg] + bz[nf];
        }
    }
}

// ============================================================================
// FUSED: LN1 (blocks 0..1999) + vgemm slice via launcher base.
// ============================================================================
__global__ __launch_bounds__(256) void ln1F(const float* __restrict__ a,
                                            const float* __restrict__ bsum,
                                            const float* __restrict__ pos,
                                            const float* __restrict__ g,
                                            const float* __restrict__ be,
                                            float* __restrict__ out,
                                            unsigned short* __restrict__ outb,
                                            VArgs V, int vbase)
{
    __shared__ __align__(16) char smem[49152];
    const int bid = blockIdx.x;
    if (bid >= 2000) { vgemm_body(smem, vbase + bid - 2000, V); return; }

    const int wave = threadIdx.x >> 6, lane = threadIdx.x & 63;
    const int row = bid * 4 + wave;
    float4 xa = reinterpret_cast<const float4*>(a + (size_t)row * 256)[lane];
    float4 xb = reinterpret_cast<const float4*>(bsum + (size_t)row * 256)[lane];
    float4 x = {xa.x + xb.x, xa.y + xb.y, xa.z + xb.z, xa.w + xb.w};
    float s  = x.x + x.y + x.z + x.w;
    float ss = x.x * x.x + x.y * x.y + x.z * x.z + x.w * x.w;
    #pragma unroll
    for (int off = 32; off > 0; off >>= 1) {
        s  += __shfl_xor(s, off);
        ss += __shfl_xor(ss, off);
    }
    float mu  = s * (1.f / 256.f);
    float var = ss * (1.f / 256.f) - mu * mu;
    float rstd = rsqrtf(var + 1e-5f);
    float4 gv = reinterpret_cast<const float4*>(g)[lane];
    float4 bv = reinterpret_cast<const float4*>(be)[lane];
    float4 o = {(x.x - mu) * rstd * gv.x + bv.x,
                (x.y - mu) * rstd * gv.y + bv.y,
                (x.z - mu) * rstd * gv.z + bv.z,
                (x.w - mu) * rstd * gv.w + bv.w};
    reinterpret_cast<float4*>(out + (size_t)row * 256)[lane] = o;
    float4 pv = reinterpret_cast<const float4*>(pos + (size_t)row * 256)[lane];
    ushort4 q4;
    q4.x = f32_to_bf16_bits(o.x + pv.x); q4.y = f32_to_bf16_bits(o.y + pv.y);
    q4.z = f32_to_bf16_bits(o.z + pv.z); q4.w = f32_to_bf16_bits(o.w + pv.w);
    *reinterpret_cast<ushort4*>(outb + (size_t)row * 256 + lane * 4) = q4;
}

// ============================================================================
// B-resident barrier-free GEMM (small GEMMs, bf16 A): C = A @ Bt^T + bias.
// CMODE: 0 = f32 out; 1 = bf16 out.
// ============================================================================
template<bool RELU, int CMODE, int BN, int K>
__global__ __launch_bounds__(256) void bgemm(const unsigned short* __restrict__ Ab,
                                             const unsigned short* __restrict__ Bt,
                                             const float* __restrict__ bias,
                                             float* __restrict__ Cf,
                                             unsigned short* __restrict__ Cb,
                                             int N)
{
    constexpr int NF   = BN / 16;
    constexpr int KF   = K / 32;
    constexpr int ROWB = K * 2;
    constexpr int FILL = BN * ROWB / 4096;

    __shared__ __align__(16) unsigned short sB[BN * K];

    const int tid = threadIdx.x;
    const int w = tid >> 6, l = tid & 63;
    const int g = l >> 4, lr = l & 15;
    const int n0 = blockIdx.x * BN;

    #pragma unroll
    for (int r = 0; r < FILL; r++) {
        int lin = (r * 256 + tid) * 16;
        int row = lin / ROWB;
        int kb  = (lin & (ROWB - 1)) ^ ((row & 7) << 4);
        async_copy16(Bt + (size_t)(n0 + row) * K + (kb >> 1), (char*)sB + lin);
    }
    asm volatile("s_waitcnt vmcnt(0)\n\ts_barrier" ::: "memory");

    float bz[NF];
    #pragma unroll
    for (int nf = 0; nf < NF; nf++) bz[nf] = bias[n0 + nf * 16 + lr];

    const int m0w = blockIdx.y * 64 + w * 16;
    const int arow = m0w + lr;

    f32x4 acc[NF];
    #pragma unroll
    for (int nf = 0; nf < NF; nf++)
        #pragma unroll
        for (int r = 0; r < 4; r++) acc[nf][r] = 0.f;

    #pragma unroll
    for (int kf = 0; kf < KF; kf++) {
        bf16x8 af = *reinterpret_cast<const bf16x8*>(Ab + (size_t)arow * K + kf * 32 + g * 8);
        #pragma unroll
        for (int nf = 0; nf < NF; nf++) {
            int brow = nf * 16 + lr;
            bf16x8 bf = *reinterpret_cast<const bf16x8*>(
                (const char*)sB + brow * ROWB + ((kf * 64 + g * 16) ^ ((brow & 7) << 4)));
            acc[nf] = __builtin_amdgcn_mfma_f32_16x16x32_bf16(af, bf, acc[nf], 0, 0, 0);
        }
    }

    #pragma unroll
    for (int nf = 0; nf < NF; nf++) {
        int col = n0 + nf * 16 + lr;
        #pragma unroll
        for (int rg = 0; rg < 4; rg++) {
            int row = m0w + g * 4 + rg;
            float v = acc[nf][rg] + bz[nf];
            if (RELU) v = fmaxf(v, 0.f);
            if constexpr (CMODE == 1)
                Cb[(size_t)row * N + col] = f32_to_bf16_bits(v);
            else
                Cf[(size_t)row * N + col] = v;
        }
    }
}

// ============================================================================
// LayerNorm: out = LN(a + b) * g + be. OM: 0 = f32 only; 1 = +bf16(out).
// ============================================================================
template<int OM>
__global__ __launch_bounds__(256) void ln_k(const float* __restrict__ a,
                                            const float* __restrict__ bsum,
                                            const float* __restrict__ g,
                                            const float* __restrict__ be,
                                            float* __restrict__ out,
                                            unsigned short* __restrict__ outb)
{
    const int wave = threadIdx.x >> 6, lane = threadIdx.x & 63;
    const int row = blockIdx.x * 4 + wave;
    float4 xa = reinterpret_cast<const float4*>(a + (size_t)row * 256)[lane];
    float4 xb = reinterpret_cast<const float4*>(bsum + (size_t)row * 256)[lane];
    float4 x = {xa.x + xb.x, xa.y + xb.y, xa.z + xb.z, xa.w + xb.w};
    float s  = x.x + x.y + x.z + x.w;
    float ss = x.x * x.x + x.y * x.y + x.z * x.z + x.w * x.w;
    #pragma unroll
    for (int off = 32; off > 0; off >>= 1) {
        s  += __shfl_xor(s, off);
        ss += __shfl_xor(ss, off);
    }
    float mu  = s * (1.f / 256.f);
    float var = ss * (1.f / 256.f) - mu * mu;
    float rstd = rsqrtf(var + 1e-5f);
    float4 gv = reinterpret_cast<const float4*>(g)[lane];
    float4 bv = reinterpret_cast<const float4*>(be)[lane];
    float4 o = {(x.x - mu) * rstd * gv.x + bv.x,
                (x.y - mu) * rstd * gv.y + bv.y,
                (x.z - mu) * rstd * gv.z + bv.z,
                (x.w - mu) * rstd * gv.w + bv.w};
    reinterpret_cast<float4*>(out + (size_t)row * 256)[lane] = o;
    if constexpr (OM == 1) {
        ushort4 q4;
        q4.x = f32_to_bf16_bits(o.x); q4.y = f32_to_bf16_bits(o.y);
        q4.z = f32_to_bf16_bits(o.z); q4.w = f32_to_bf16_bits(o.w);
        *reinterpret_cast<ushort4*>(outb + (size_t)row * 256 + lane * 4) = q4;
    }
}

// ============================================================================
// Deformable sampling (r14-verified): 2 tokens/block, 2 channels/thread.
// ============================================================================
__device__ inline unsigned int samp2(const unsigned short* __restrict__ v,
                                     int b, int st, int Wl, int Hl,
                                     int x, int y, int hc)
{
    bool valid = (x >= 0) & (x < Wl) & (y >= 0) & (y < Hl);
    int xc = min(max(x, 0), Wl - 1);
    int yc = min(max(y, 0), Hl - 1);
    size_t idx = ((size_t)(b * S_ + st + yc * Wl + xc)) * 256 + hc;
    unsigned int val = *reinterpret_cast<const unsigned int*>(v + idx);
    return valid ? val : 0u;
}

__global__ __launch_bounds__(256) void deform_k(const float* __restrict__ rp,
                                                const float* __restrict__ oa,
                                                const unsigned short* __restrict__ value,
                                                unsigned short* __restrict__ ca)
{
    const int tk = threadIdx.x >> 7;
    const int tok = blockIdx.x * 2 + tk;
    const int b = tok / NQ_;
    const int h = (threadIdx.x >> 4) & 7;
    const int cp = threadIdx.x & 15;
    const int hc = h * 32 + cp * 2;

    const float* awp = oa + (size_t)tok * 384 + 256 + h * 16;
    float w[16];
    float mx = -1e30f;
    #pragma unroll
    for (int i = 0; i < 16; i++) { w[i] = awp[i]; mx = fmaxf(mx, w[i]); }
    float sum = 0.f;
    #pragma unroll
    for (int i = 0; i < 16; i++) { w[i] = __expf(w[i] - mx); sum += w[i]; }
    const float inv = 1.f / sum;

    const float* rpp  = rp + (size_t)tok * (L_ * 4);
    const float* offp = oa + (size_t)tok * 384 + h * 32;

    const int lvlW[4] = {128, 64, 32, 16};
    const int lvlS[4] = {0, 16384, 20480, 21504};

    float acc0 = 0.f, acc1 = 0.f;
    #pragma unroll
    for (int l = 0; l < 4; l++) {
        const int Wl = lvlW[l], Hl = lvlW[l], st = lvlS[l];
        const float cx = rpp[l * 4 + 0], cy = rpp[l * 4 + 1];
        const float cw = rpp[l * 4 + 2], chh = rpp[l * 4 + 3];
        #pragma unroll
        for (int p = 0; p < 4; p++) {
            float ox = offp[l * 8 + p * 2 + 0];
            float oy = offp[l * 8 + p * 2 + 1];
            float lx = (cx + ox * 0.25f * cw * 0.5f) * Wl - 0.5f;
            float ly = (cy + oy * 0.25f * chh * 0.5f) * Hl - 0.5f;
            float x0f = floorf(lx), y0f = floorf(ly);
            float tx = lx - x0f, ty = ly - y0f;
            int x0 = (int)x0f, y0 = (int)y0f;
            unsigned int u00 = samp2(value, b, st, Wl, Hl, x0,     y0,     hc);
            unsigned int u01 = samp2(value, b, st, Wl, Hl, x0 + 1, y0,     hc);
            unsigned int u10 = samp2(value, b, st, Wl, Hl, x0,     y0 + 1, hc);
            unsigned int u11 = samp2(value, b, st, Wl, Hl, x0 + 1, y0 + 1, hc);
            float w00 = (1.f - tx) * (1.f - ty), w01 = tx * (1.f - ty);
            float w10 = (1.f - tx) * ty,         w11 = tx * ty;
            float g0 = bf16_bits_to_f32((unsigned short)u00) * w00
                     + bf16_bits_to_f32((unsigned short)u01) * w01
                     + bf16_bits_to_f32((unsigned short)u10) * w10
                     + bf16_bits_to_f32((unsigned short)u11) * w11;
            float g1 = bf16_bits_to_f32((unsigned short)(u00 >> 16)) * w00
                     + bf16_bits_to_f32((unsigned short)(u01 >> 16)) * w01
                     + bf16_bits_to_f32((unsigned short)(u10 >> 16)) * w10
                     + bf16_bits_to_f32((unsigned short)(u11 >> 16)) * w11;
            float wa = w[l * 4 + p] * inv;
            acc0 += wa * g0;
            acc1 += wa * g1;
        }
    }
    unsigned int packed = ((unsigned)f32_to_bf16_bits(acc0)) | (((unsigned)f32_to_bf16_bits(acc1)) << 16);
    *reinterpret_cast<unsigned int*>(ca + (size_t)tok * 256 + hc) = packed;
}

// ============================================================================
extern "C" void kernel_launch(void* const* d_in, const int* in_sizes, int n_in,
                              void* d_out, int out_size, void* d_ws, size_t ws_size,
                              hipStream_t stream)
{
    const float* query      = (const float*)d_in[0];
    const float* query_pos  = (const float*)d_in[1];
    const float* ref_pts    = (const float*)d_in[2];
    const float* input_flat = (const float*)d_in[3];
    const float* Wq = (const float*)d_in[6];  const float* bq = (const float*)d_in[7];
    const float* Wk = (const float*)d_in[8];  const float* bk = (const float*)d_in[9];
    const float* Wv = (const float*)d_in[10]; const float* bv = (const float*)d_in[11];
    const float* Wo = (const float*)d_in[12]; const float* bo = (const float*)d_in[13];
    const float* ln1g = (const float*)d_in[14]; const float* ln1b = (const float*)d_in[15];
    const float* W_off = (const float*)d_in[16]; const float* b_off = (const float*)d_in[17];
    const float* W_attn = (const float*)d_in[18]; const float* b_attn = (const float*)d_in[19];
    const float* W_val = (const float*)d_in[20]; const float* b_val = (const float*)d_in[21];
    const float* W_cout = (const float*)d_in[22]; const float* b_cout = (const float*)d_in[23];
    const float* ln2g = (const float*)d_in[24]; const float* ln2b = (const float*)d_in[25];
    const float* W1 = (const float*)d_in[26]; const float* b1 = (const float*)d_in[27];
    const float* W2 = (const float*)d_in[28]; const float* b2 = (const float*)d_in[29];
    const float* ln3g = (const float*)d_in[30]; const float* ln3b = (const float*)d_in[31];
    float* out = (float*)d_out;

    // ---- workspace arena ----
    char* base = (char*)d_ws;
    size_t off = 0;
    auto alloc = [&](size_t bytes) { void* p = base + off; off += (bytes + 255) & ~(size_t)255; return p; };
    unsigned short* value_bf = (unsigned short*)alloc((size_t)B_ * S_ * 256 * 2);   // 89.1 MB
    unsigned short* qk_bf = (unsigned short*)alloc((size_t)NTOK * 1024 * 2);        // qk ∪ h_bf
    unsigned short* h_bf = qk_bf;
    unsigned short* vt = (unsigned short*)alloc((size_t)B_ * 256 * 1024 * 2);       // 4.2 MB
    float* oa_buf = (float*)alloc((size_t)NTOK * 384 * 4);
    float* tmp0   = (float*)alloc((size_t)NTOK * 256 * 4);
    float* x1     = (float*)alloc((size_t)NTOK * 256 * 4);
    float* x2     = (float*)alloc((size_t)NTOK * 256 * 4);
    unsigned short* sc_bf  = (unsigned short*)alloc((size_t)NTOK * 256 * 2);
    unsigned short* q_bf   = (unsigned short*)alloc((size_t)NTOK * 256 * 2);
    unsigned short* qp_bf  = (unsigned short*)alloc((size_t)NTOK * 256 * 2);
    unsigned short* x1p_bf = (unsigned short*)alloc((size_t)NTOK * 256 * 2);
    unsigned short* x2_bf  = (unsigned short*)alloc((size_t)NTOK * 256 * 2);
    unsigned short* wqkv  = (unsigned short*)alloc(768 * 256 * 2);
    unsigned short* wo    = (unsigned short*)alloc(256 * 256 * 2);
    unsigned short* woa   = (unsigned short*)alloc(384 * 256 * 2);
    unsigned short* wval  = (unsigned short*)alloc(256 * 256 * 2);
    unsigned short* wcout = (unsigned short*)alloc(256 * 256 * 2);
    unsigned short* w1t   = (unsigned short*)alloc(1024 * 256 * 2);
    unsigned short* w2t   = (unsigned short*)alloc(256 * 1024 * 2);
    float* qkvbias = (float*)alloc(768 * 4);
    float* oabias  = (float*)alloc(384 * 4);

    dim3 blk(256);

    // ---- fused prep ----
    PrepArgs P;
    P.wsrc[0] = Wq;    P.wdst[0] = wqkv;              P.wK[0] = 256;  P.wN[0] = 256;
    P.wsrc[1] = Wk;    P.wdst[1] = wqkv + 256 * 256;  P.wK[1] = 256;  P.wN[1] = 256;
    P.wsrc[2] = Wv;    P.wdst[2] = wqkv + 512 * 256;  P.wK[2] = 256;  P.wN[2] = 256;
    P.wsrc[3] = Wo;    P.wdst[3] = wo;                P.wK[3] = 256;  P.wN[3] = 256;
    P.wsrc[4] = W_off; P.wdst[4] = woa;               P.wK[4] = 256;  P.wN[4] = 256;
    P.wsrc[5] = W_attn;P.wdst[5] = woa + 256 * 256;   P.wK[5] = 256;  P.wN[5] = 128;
    P.wsrc[6] = W_val; P.wdst[6] = wval;              P.wK[6] = 256;  P.wN[6] = 256;
    P.wsrc[7] = W_cout;P.wdst[7] = wcout;             P.wK[7] = 256;  P.wN[7] = 256;
    P.wsrc[8] = W1;    P.wdst[8] = w1t;               P.wK[8] = 256;  P.wN[8] = 1024;
    P.wsrc[9] = W2;    P.wdst[9] = w2t;               P.wK[9] = 1024; P.wN[9] = 256;
    P.bq = bq; P.bk = bk; P.bv = bv; P.boff = b_off; P.battn = b_attn;
    P.qkvb = qkvbias; P.oab = oabias;
    P.query = query; P.qpos = query_pos; P.q_bf = q_bf; P.qp_bf = qp_bf;
    prep_k<<<891, blk, 0, stream>>>(P);

    VArgs V;
    V.Af = input_flat; V.Bt = wval; V.bias = b_val; V.Cb = value_bf;

    // ---- self-attention block, vgemm slices in LOW-VGPR hosts only ----
    qkvF<<<1500 + 500, blk, 0, stream>>>(qp_bf, q_bf, wqkv, qkvbias, qk_bf, vt, V);   // slice [0,500)
    fattn_k<<<dim3(16, NH_, B_), blk, 0, stream>>>(qk_bf, vt, sc_bf);                 // standalone
    woF<<<500 + 250, blk, 0, stream>>>(sc_bf, wo, bo, tmp0, V);                       // slice [500,750)
    ln1F<<<2000 + 250, blk, 0, stream>>>(query, tmp0, query_pos, ln1g, ln1b, x1, x1p_bf, V, 750); // [750,1000)
    woaF<<<750 + 350, blk, 0, stream>>>(x1p_bf, woa, oabias, oa_buf, V, 1000);        // slice [1000,1350)
    vgemmS<<<1370, blk, 0, stream>>>(V, 1350);                                        // [1350,2720)

    // ---- deformable cross-attention ----
    deform_k<<<NTOK / 2, blk, 0, stream>>>(ref_pts, oa_buf, value_bf, sc_bf);
    bgemm<false, 0,  64, 256><<<dim3(4, 125), blk, 0, stream>>>(sc_bf, wcout, b_cout, tmp0, nullptr, 256);
    ln_k<1><<<NTOK / 4, blk, 0, stream>>>(x1, tmp0, ln2g, ln2b, x2, x2_bf);

    // ---- FFN ----
    bgemm<true,  1,  64, 256><<<dim3(16, 125), blk, 0, stream>>>(x2_bf, w1t, b1, nullptr, h_bf, 1024);
    bgemm<false, 0,  32, 1024><<<dim3(8, 125), blk, 0, stream>>>(h_bf, w2t, b2, tmp0, nullptr, 256);
    ln_k<0><<<NTOK / 4, blk, 0, stream>>>(x2, tmp0, ln3g, ln3b, out, nullptr);
}

// Round 18
// 252.402 us; speedup vs baseline: 1.3377x; 1.2658x over previous
//
#include <hip/hip_runtime.h>
#include <hip/hip_bf16.h>

#define B_   8
#define NQ_  1000
#define D_   256
#define NH_  8
#define L_   4
#define P_   4
#define DFF_ 1024
#define HD_  32
#define S_   21760
#define NTOK (B_*NQ_)

typedef short  bf16x8 __attribute__((ext_vector_type(8)));
typedef float  f32x4  __attribute__((ext_vector_type(4)));

#define WAITBAR(N) asm volatile("s_waitcnt vmcnt(" #N ") lgkmcnt(0)\n\ts_barrier" ::: "memory")
#define ENDBAR()   asm volatile("s_barrier" ::: "memory")

__device__ inline unsigned short f32_to_bf16_bits(float f) {
    unsigned int u = __float_as_uint(f);
    unsigned int rounding = 0x7FFFu + ((u >> 16) & 1u);
    u += rounding;
    return (unsigned short)(u >> 16);
}
__device__ inline float bf16_bits_to_f32(unsigned short b) {
    return __uint_as_float(((unsigned int)b) << 16);
}
// {bf16_trunc(f1)<<16 | bf16_trunc(f0)} in ONE v_perm_b32
__device__ inline unsigned int pack_trunc(float f0, float f1) {
    return __builtin_amdgcn_perm(__float_as_uint(f1), __float_as_uint(f0), 0x07060302u);
}
__device__ inline void async_copy16(const void* g, void* l) {
    __builtin_amdgcn_global_load_lds((const __attribute__((address_space(1))) unsigned int*)g,
                                     (__attribute__((address_space(3))) unsigned int*)l, 16, 0, 0);
}

// ============================================================================
// Fused prep. Blocks: 0..639 weight transpose (10 jobs); 640 bias pack
// (qkv 768 + oa 384); 641..890 q_bf / qp_bf (ILP-batched).
// ============================================================================
struct PrepArgs {
    const float* wsrc[10];
    unsigned short* wdst[10];
    int wK[10], wN[10];
    const float* bq; const float* bk; const float* bv; const float* boff; const float* battn;
    float* qkvb; float* oab;
    const float* query; const float* qpos;
    unsigned short* q_bf; unsigned short* qp_bf;
};
__global__ __launch_bounds__(256) void prep_k(PrepArgs P)
{
    const int bid = blockIdx.x, tid = threadIdx.x;
    if (bid < 640) {
        const int job = bid >> 6, tile = bid & 63;
        const int K = P.wK[job], N = P.wN[job];
        const int tilesN = N >> 6;
        if (tile >= (K >> 6) * tilesN) return;
        const int kt = tile / tilesN, nt = tile - kt * tilesN;
        const int k0 = kt * 64, n0 = nt * 64;
        __shared__ unsigned short t_[64][65];
        const float* src = P.wsrc[job];
        unsigned short* dst = P.wdst[job];
        const int cc = tid & 63, rr = tid >> 6;
        #pragma unroll
        for (int i = 0; i < 16; i++) {
            int k = i * 4 + rr;
            t_[k][cc] = f32_to_bf16_bits(src[(size_t)(k0 + k) * N + n0 + cc]);
        }
        __syncthreads();
        #pragma unroll
        for (int i = 0; i < 16; i++) {
            int n = i * 4 + rr;
            dst[(size_t)(n0 + n) * K + k0 + cc] = t_[cc][n];
        }
    } else if (bid == 640) {
        P.qkvb[tid]       = P.bq[tid];
        P.qkvb[256 + tid] = P.bk[tid];
        P.qkvb[512 + tid] = P.bv[tid];
        P.oab[tid]        = P.boff[tid];
        if (tid < 128) P.oab[256 + tid] = P.battn[tid];
    } else {
        const int base = (bid - 641) * 1024 + tid;
        float4 fq[4][2], fp[4][2];
        #pragma unroll
        for (int i = 0; i < 4; i++) {
            const float* q = P.query + (size_t)(base + i * 256) * 8;
            const float* p = P.qpos  + (size_t)(base + i * 256) * 8;
            fq[i][0] = *reinterpret_cast<const float4*>(q);
            fq[i][1] = *reinterpret_cast<const float4*>(q + 4);
            fp[i][0] = *reinterpret_cast<const float4*>(p);
            fp[i][1] = *reinterpret_cast<const float4*>(p + 4);
        }
        #pragma unroll
        for (int i = 0; i < 4; i++) {
            uint4 tq, tp;
            tq.x = pack_trunc(fq[i][0].x, fq[i][0].y);
            tq.y = pack_trunc(fq[i][0].z, fq[i][0].w);
            tq.z = pack_trunc(fq[i][1].x, fq[i][1].y);
            tq.w = pack_trunc(fq[i][1].z, fq[i][1].w);
            tp.x = pack_trunc(fq[i][0].x + fp[i][0].x, fq[i][0].y + fp[i][0].y);
            tp.y = pack_trunc(fq[i][0].z + fp[i][0].z, fq[i][0].w + fp[i][0].w);
            tp.z = pack_trunc(fq[i][1].x + fp[i][1].x, fq[i][1].y + fp[i][1].y);
            tp.w = pack_trunc(fq[i][1].z + fp[i][1].z, fq[i][1].w + fp[i][1].w);
            *reinterpret_cast<uint4*>(P.q_bf  + (size_t)(base + i * 256) * 8) = tq;
            *reinterpret_cast<uint4*>(P.qp_bf + (size_t)(base + i * 256) * 8) = tp;
        }
    }
}

// ============================================================================
// Value-projection GEMM with FUSED f32->bf16 (r14-verified).
// grid (2, 1360), block 256.
// ============================================================================
__global__ __launch_bounds__(256) void vgemmF(const float* __restrict__ Af,
                                              const unsigned short* __restrict__ Bt,
                                              const float* __restrict__ bias,
                                              unsigned short* __restrict__ Cb)
{
    constexpr int K = 256;
    constexpr int N = 256;
    __shared__ __align__(16) float          sA[2][128 * 32];   // 16 KB each
    __shared__ __align__(16) unsigned short sB[2][128 * 32];   // 8 KB each
    const int tid = threadIdx.x;
    const int w = tid >> 6, l = tid & 63;
    const int n0 = blockIdx.x * 128, m0 = blockIdx.y * 128;
    const int wr = w >> 1, wc = w & 1;
    const int lq = l & 15, g = l >> 4;

    f32x4 acc[4][4];
    #pragma unroll
    for (int i = 0; i < 4; i++)
        #pragma unroll
        for (int j = 0; j < 4; j++)
            #pragma unroll
            for (int r = 0; r < 4; r++) acc[i][j][r] = 0.f;

    auto issueA = [&](int t, int buf) {
        #pragma unroll
        for (int r = 0; r < 4; r++) {
            int lin = (r * 256 + tid) * 16;            // physical LDS byte
            int row = lin >> 7;                        // 128B rows (32 f32)
            int kb  = (lin & 127) ^ ((row & 7) << 4);  // logical unit (16B grain)
            async_copy16(Af + (size_t)(m0 + row) * K + t * 32 + (kb >> 2),
                         (char*)sA[buf] + lin);
        }
    };
    auto issueB = [&](int t, int buf) {
        #pragma unroll
        for (int r = 0; r < 2; r++) {
            int lin = (r * 256 + tid) * 16;
            int row = lin >> 6;                        // 64B rows (32 bf16)
            int kb  = (lin & 63) ^ ((row & 3) << 4);
            async_copy16(Bt + (size_t)(n0 + row) * K + t * 32 + (kb >> 1),
                         (char*)sB[buf] + lin);
        }
    };

    issueA(0, 0);
    issueB(0, 0);

    for (int t = 0; t < 8; t++) {
        const int cur = t & 1;
        if (t + 1 < 8) {
            issueA(t + 1, cur ^ 1);
            issueB(t + 1, cur ^ 1);
            WAITBAR(6);
        } else {
            WAITBAR(0);
        }

        bf16x8 afr[4], bfr[4];
        #pragma unroll
        for (int mi = 0; mi < 4; mi++) {
            int row = wr * 64 + mi * 16 + lq;
            int sw  = (row & 7) << 4;
            int p0  = (g * 32) ^ sw;
            const char* p = (const char*)sA[cur] + row * 128;
            float4 a0 = *reinterpret_cast<const float4*>(p + p0);
            float4 a1 = *reinterpret_cast<const float4*>(p + (p0 ^ 16));
            uint4 u;
            u.x = pack_trunc(a0.x, a0.y);
            u.y = pack_trunc(a0.z, a0.w);
            u.z = pack_trunc(a1.x, a1.y);
            u.w = pack_trunc(a1.z, a1.w);
            afr[mi] = *reinterpret_cast<bf16x8*>(&u);
        }
        #pragma unroll
        for (int ni = 0; ni < 4; ni++) {
            int row = wc * 64 + ni * 16 + lq;
            int off = (g * 16) ^ ((row & 3) << 4);
            bfr[ni] = *reinterpret_cast<const bf16x8*>((const char*)sB[cur] + row * 64 + off);
        }
        #pragma unroll
        for (int mi = 0; mi < 4; mi++)
            #pragma unroll
            for (int ni = 0; ni < 4; ni++)
                acc[mi][ni] = __builtin_amdgcn_mfma_f32_16x16x32_bf16(
                    afr[mi], bfr[ni], acc[mi][ni], 0, 0, 0);
        ENDBAR();
    }

    #pragma unroll
    for (int mi = 0; mi < 4; mi++) {
        #pragma unroll
        for (int ni = 0; ni < 4; ni++) {
            int col = n0 + wc * 64 + ni * 16 + lq;
            float bz = bias[col];
            #pragma unroll
            for (int rg = 0; rg < 4; rg++) {
                int row = m0 + wr * 64 + mi * 16 + g * 4 + rg;
                Cb[(size_t)row * N + col] = f32_to_bf16_bits(acc[mi][ni][rg] + bz);
            }
        }
    }
}

// ============================================================================
// Fused q/k/v projection: one launch, grid (12, 125). Columns 0-511 = q|k
// (A = qp_bf, row-major out); columns 512-767 = v (A = q_bf, vt layout out).
// ============================================================================
__global__ __launch_bounds__(256) void qkv_gemm(const unsigned short* __restrict__ qp_bf,
                                                const unsigned short* __restrict__ q_bf,
                                                const unsigned short* __restrict__ Bt,
                                                const float* __restrict__ bias,
                                                unsigned short* __restrict__ qk_out,
                                                unsigned short* __restrict__ vt_out)
{
    constexpr int K = 256;
    constexpr int BN = 64;
    __shared__ __align__(16) unsigned short sB[BN * K];

    const int tid = threadIdx.x;
    const int w = tid >> 6, l = tid & 63;
    const int g = l >> 4, lr = l & 15;
    const int n0 = blockIdx.x * BN;
    const bool isV = (n0 >= 512);
    const unsigned short* Ab = isV ? q_bf : qp_bf;

    #pragma unroll
    for (int r = 0; r < 8; r++) {
        int lin = (r * 256 + tid) * 16;
        int row = lin >> 9;
        int kb  = (lin & 511) ^ ((row & 7) << 4);
        async_copy16(Bt + (size_t)(n0 + row) * K + (kb >> 1), (char*)sB + lin);
    }
    asm volatile("s_waitcnt vmcnt(0)\n\ts_barrier" ::: "memory");

    float bz[4];
    #pragma unroll
    for (int nf = 0; nf < 4; nf++) bz[nf] = bias[n0 + nf * 16 + lr];

    const int m0w = blockIdx.y * 64 + w * 16;
    const int arow = m0w + lr;

    f32x4 acc[4];
    #pragma unroll
    for (int nf = 0; nf < 4; nf++)
        #pragma unroll
        for (int r = 0; r < 4; r++) acc[nf][r] = 0.f;

    #pragma unroll
    for (int kf = 0; kf < 8; kf++) {
        bf16x8 af = *reinterpret_cast<const bf16x8*>(Ab + (size_t)arow * K + kf * 32 + g * 8);
        #pragma unroll
        for (int nf = 0; nf < 4; nf++) {
            int brow = nf * 16 + lr;
            bf16x8 bf = *reinterpret_cast<const bf16x8*>(
                (const char*)sB + brow * 512 + ((kf * 64 + g * 16) ^ ((brow & 7) << 4)));
            acc[nf] = __builtin_amdgcn_mfma_f32_16x16x32_bf16(af, bf, acc[nf], 0, 0, 0);
        }
    }

    if (!isV) {
        #pragma unroll
        for (int nf = 0; nf < 4; nf++) {
            int col = n0 + nf * 16 + lr;
            #pragma unroll
            for (int rg = 0; rg < 4; rg++) {
                int row = m0w + g * 4 + rg;
                qk_out[(size_t)row * 512 + col] = f32_to_bf16_bits(acc[nf][rg] + bz[nf]);
            }
        }
    } else {
        #pragma unroll
        for (int nf = 0; nf < 4; nf++) {
            int col = n0 - 512 + nf * 16 + lr;
            int row0 = m0w + g * 4;
            int bb = row0 / 1000;
            int key = row0 - bb * 1000;
            ushort4 q4;
            q4.x = f32_to_bf16_bits(acc[nf][0] + bz[nf]);
            q4.y = f32_to_bf16_bits(acc[nf][1] + bz[nf]);
            q4.z = f32_to_bf16_bits(acc[nf][2] + bz[nf]);
            q4.w = f32_to_bf16_bits(acc[nf][3] + bz[nf]);
            *reinterpret_cast<ushort4*>(vt_out + (size_t)bb * 262144 + (size_t)col * 1024 + key) = q4;
        }
    }
}

// ============================================================================
// B-resident barrier-free GEMM (small GEMMs, bf16 A): C = A @ Bt^T + bias.
// CMODE: 0 = f32 out; 1 = bf16 out.
// ============================================================================
template<bool RELU, int CMODE, int BN, int K>
__global__ __launch_bounds__(256) void bgemm(const unsigned short* __restrict__ Ab,
                                             const unsigned short* __restrict__ Bt,
                                             const float* __restrict__ bias,
                                             float* __restrict__ Cf,
                                             unsigned short* __restrict__ Cb,
                                             int N)
{
    constexpr int NF   = BN / 16;
    constexpr int KF   = K / 32;
    constexpr int ROWB = K * 2;
    constexpr int FILL = BN * ROWB / 4096;

    __shared__ __align__(16) unsigned short sB[BN * K];

    const int tid = threadIdx.x;
    const int w = tid >> 6, l = tid & 63;
    const int g = l >> 4, lr = l & 15;
    const int n0 = blockIdx.x * BN;

    #pragma unroll
    for (int r = 0; r < FILL; r++) {
        int lin = (r * 256 + tid) * 16;
        int row = lin / ROWB;
        int kb  = (lin & (ROWB - 1)) ^ ((row & 7) << 4);
        async_copy16(Bt + (size_t)(n0 + row) * K + (kb >> 1), (char*)sB + lin);
    }
    asm volatile("s_waitcnt vmcnt(0)\n\ts_barrier" ::: "memory");

    float bz[NF];
    #pragma unroll
    for (int nf = 0; nf < NF; nf++) bz[nf] = bias[n0 + nf * 16 + lr];

    const int m0w = blockIdx.y * 64 + w * 16;
    const int arow = m0w + lr;

    f32x4 acc[NF];
    #pragma unroll
    for (int nf = 0; nf < NF; nf++)
        #pragma unroll
        for (int r = 0; r < 4; r++) acc[nf][r] = 0.f;

    #pragma unroll
    for (int kf = 0; kf < KF; kf++) {
        bf16x8 af = *reinterpret_cast<const bf16x8*>(Ab + (size_t)arow * K + kf * 32 + g * 8);
        #pragma unroll
        for (int nf = 0; nf < NF; nf++) {
            int brow = nf * 16 + lr;
            bf16x8 bf = *reinterpret_cast<const bf16x8*>(
                (const char*)sB + brow * ROWB + ((kf * 64 + g * 16) ^ ((brow & 7) << 4)));
            acc[nf] = __builtin_amdgcn_mfma_f32_16x16x32_bf16(af, bf, acc[nf], 0, 0, 0);
        }
    }

    #pragma unroll
    for (int nf = 0; nf < NF; nf++) {
        int col = n0 + nf * 16 + lr;
        #pragma unroll
        for (int rg = 0; rg < 4; rg++) {
            int row = m0w + g * 4 + rg;
            float v = acc[nf][rg] + bz[nf];
            if (RELU) v = fmaxf(v, 0.f);
            if constexpr (CMODE == 1)
                Cb[(size_t)row * N + col] = f32_to_bf16_bits(v);
            else
                Cf[(size_t)row * N + col] = v;
        }
    }
}

// ============================================================================
// MFMA flash self-attention, K/V double-buffered (verified).
// ============================================================================
__global__ __launch_bounds__(256) void fattn_k(const unsigned short* __restrict__ qk,
                                               const unsigned short* __restrict__ vt,
                                               unsigned short* __restrict__ sa)
{
    const int b = blockIdx.z, h = blockIdx.y;
    const int tid = threadIdx.x;
    const int w = tid >> 6, l = tid & 63;
    const int lq = l & 15, g = l >> 4;
    const int q0 = blockIdx.x * 64 + w * 16;

    __shared__ __align__(16) unsigned short Ks[2][128 * 32];
    __shared__ __align__(16) unsigned short Vs[2][32 * 128];
    __shared__ __align__(16) unsigned short Ps[4][16 * 128];

    int qrow = q0 + lq; if (qrow > NQ_ - 1) qrow = NQ_ - 1;
    const bf16x8 qfrag = *reinterpret_cast<const bf16x8*>(
        qk + ((size_t)(b * NQ_ + qrow)) * 512 + h * 32 + g * 8);

    f32x4 O0 = {0.f, 0.f, 0.f, 0.f}, O1 = {0.f, 0.f, 0.f, 0.f};
    float m = -1e30f, lsum = 0.f;
    const float scale = 0.17677669529663687f;

    const size_t kbase = (size_t)b * (NQ_ * 512) + 256 + h * 32;
    const size_t vbase = (size_t)b * 262144 + (size_t)(h * 32) * 1024;
    const int swz = (lq & 7) << 4;

    auto issueKV = [&](int kt, int buf) {
        #pragma unroll
        for (int r = 0; r < 2; r++) {
            int lin = (r * 256 + tid) * 16;
            int krow = lin >> 6;
            int kb = (lin & 63) ^ ((krow & 7) << 4);
            async_copy16(qk + kbase + (size_t)(kt * 128 + krow) * 512 + (kb >> 1),
                         (char*)Ks[buf] + lin);
            int d = lin >> 8;
            int vb = (lin & 255) ^ ((d & 7) << 4);
            async_copy16(vt + vbase + (size_t)d * 1024 + kt * 128 + (vb >> 1),
                         (char*)Vs[buf] + lin);
        }
    };

    issueKV(0, 0);

    for (int kt = 0; kt < 8; kt++) {
        const int k0 = kt * 128;
        const int cur = kt & 1;
        asm volatile("s_waitcnt vmcnt(0) lgkmcnt(0)\n\ts_barrier" ::: "memory");
        if (kt < 7) issueKV(kt + 1, cur ^ 1);

        const unsigned short* Kc = Ks[cur];
        const unsigned short* Vc = Vs[cur];

        float t[8][4];
        float tmax = -1e30f;
        const bool tail = (k0 + 128 > NQ_);
        #pragma unroll
        for (int ni = 0; ni < 8; ni++) {
            int row = ni * 16 + lq;
            bf16x8 kf = *reinterpret_cast<const bf16x8*>(
                (const char*)Kc + row * 64 + ((g * 16) ^ swz));
            f32x4 st = __builtin_amdgcn_mfma_f32_16x16x32_bf16(
                kf, qfrag, (f32x4){0.f, 0.f, 0.f, 0.f}, 0, 0, 0);
            #pragma unroll
            for (int rg = 0; rg < 4; rg++) {
                float tv = st[rg] * scale;
                if (tail) {
                    int key = k0 + ni * 16 + g * 4 + rg;
                    tv = (key < NQ_) ? tv : -1e30f;
                }
                t[ni][rg] = tv;
                tmax = fmaxf(tmax, tv);
            }
        }
        tmax = fmaxf(tmax, __shfl_xor(tmax, 16));
        tmax = fmaxf(tmax, __shfl_xor(tmax, 32));
        float mnew = fmaxf(m, tmax);
        float corr = __expf(m - mnew);
        m = mnew;

        float rs = 0.f;
        unsigned int pk[8][2];
        #pragma unroll
        for (int ni = 0; ni < 8; ni++) {
            float p0 = __expf(t[ni][0] - mnew);
            float p1 = __expf(t[ni][1] - mnew);
            float p2 = __expf(t[ni][2] - mnew);
            float p3 = __expf(t[ni][3] - mnew);
            rs += (p0 + p1) + (p2 + p3);
            pk[ni][0] = ((unsigned)f32_to_bf16_bits(p0)) | (((unsigned)f32_to_bf16_bits(p1)) << 16);
            pk[ni][1] = ((unsigned)f32_to_bf16_bits(p2)) | (((unsigned)f32_to_bf16_bits(p3)) << 16);
        }
        rs += __shfl_xor(rs, 16);
        rs += __shfl_xor(rs, 32);
        lsum = lsum * corr + rs;

        float c0 = __shfl(corr, g * 4 + 0);
        float c1 = __shfl(corr, g * 4 + 1);
        float c2 = __shfl(corr, g * 4 + 2);
        float c3 = __shfl(corr, g * 4 + 3);
        O0[0] *= c0; O0[1] *= c1; O0[2] *= c2; O0[3] *= c3;
        O1[0] *= c0; O1[1] *= c1; O1[2] *= c2; O1[3] *= c3;

        unsigned short* Pw = Ps[w];
        #pragma unroll
        for (int ni = 0; ni < 8; ni++) {
            int byteoff = lq * 256 + ((ni * 32 + g * 8) ^ swz);
            *reinterpret_cast<uint2*>((char*)Pw + byteoff) = make_uint2(pk[ni][0], pk[ni][1]);
        }

        #pragma unroll
        for (int c = 0; c < 4; c++) {
            int rb = (c * 64 + g * 16) ^ swz;
            bf16x8 pa = *reinterpret_cast<const bf16x8*>((const char*)Pw + lq * 256 + rb);
            bf16x8 v0 = *reinterpret_cast<const bf16x8*>((const char*)Vc + lq * 256 + rb);
            bf16x8 v1 = *reinterpret_cast<const bf16x8*>((const char*)Vc + (16 + lq) * 256 + rb);
            O0 = __builtin_amdgcn_mfma_f32_16x16x32_bf16(pa, v0, O0, 0, 0, 0);
            O1 = __builtin_amdgcn_mfma_f32_16x16x32_bf16(pa, v1, O1, 0, 0, 0);
        }
    }

    float linv = 1.f / lsum;
    float i0 = __shfl(linv, g * 4 + 0);
    float i1 = __shfl(linv, g * 4 + 1);
    float i2 = __shfl(linv, g * 4 + 2);
    float i3 = __shfl(linv, g * 4 + 3);
    float iv[4] = {i0, i1, i2, i3};
    #pragma unroll
    for (int rg = 0; rg < 4; rg++) {
        int qg = q0 + g * 4 + rg;
        if (qg < NQ_) {
            size_t obase = ((size_t)(b * NQ_ + qg)) * 256 + h * 32;
            sa[obase + lq]      = f32_to_bf16_bits(O0[rg] * iv[rg]);
            sa[obase + 16 + lq] = f32_to_bf16_bits(O1[rg] * iv[rg]);
        }
    }
}

// ============================================================================
// LayerNorm: out = LN(a + b) * g + be. OM: 0 = f32 only; 1 = +bf16(out);
// 2 = +bf16(out + pos).
// ============================================================================
template<int OM>
__global__ __launch_bounds__(256) void ln_k(const float* __restrict__ a,
                                            const float* __restrict__ bsum,
                                            const float* __restrict__ pos,
                                            const float* __restrict__ g,
                                            const float* __restrict__ be,
                                            float* __restrict__ out,
                                            unsigned short* __restrict__ outb)
{
    const int wave = threadIdx.x >> 6, lane = threadIdx.x & 63;
    const int row = blockIdx.x * 4 + wave;
    float4 xa = reinterpret_cast<const float4*>(a + (size_t)row * 256)[lane];
    float4 xb = reinterpret_cast<const float4*>(bsum + (size_t)row * 256)[lane];
    float4 x = {xa.x + xb.x, xa.y + xb.y, xa.z + xb.z, xa.w + xb.w};
    float s  = x.x + x.y + x.z + x.w;
    float ss = x.x * x.x + x.y * x.y + x.z * x.z + x.w * x.w;
    #pragma unroll
    for (int off = 32; off > 0; off >>= 1) {
        s  += __shfl_xor(s, off);
        ss += __shfl_xor(ss, off);
    }
    float mu  = s * (1.f / 256.f);
    float var = ss * (1.f / 256.f) - mu * mu;
    float rstd = rsqrtf(var + 1e-5f);
    float4 gv = reinterpret_cast<const float4*>(g)[lane];
    float4 bv = reinterpret_cast<const float4*>(be)[lane];
    float4 o = {(x.x - mu) * rstd * gv.x + bv.x,
                (x.y - mu) * rstd * gv.y + bv.y,
                (x.z - mu) * rstd * gv.z + bv.z,
                (x.w - mu) * rstd * gv.w + bv.w};
    reinterpret_cast<float4*>(out + (size_t)row * 256)[lane] = o;
    if constexpr (OM == 1) {
        ushort4 q4;
        q4.x = f32_to_bf16_bits(o.x); q4.y = f32_to_bf16_bits(o.y);
        q4.z = f32_to_bf16_bits(o.z); q4.w = f32_to_bf16_bits(o.w);
        *reinterpret_cast<ushort4*>(outb + (size_t)row * 256 + lane * 4) = q4;
    } else if constexpr (OM == 2) {
        float4 pv = reinterpret_cast<const float4*>(pos + (size_t)row * 256)[lane];
        ushort4 q4;
        q4.x = f32_to_bf16_bits(o.x + pv.x); q4.y = f32_to_bf16_bits(o.y + pv.y);
        q4.z = f32_to_bf16_bits(o.z + pv.z); q4.w = f32_to_bf16_bits(o.w + pv.w);
        *reinterpret_cast<ushort4*>(outb + (size_t)row * 256 + lane * 4) = q4;
    }
}

// ============================================================================
// Deformable sampling: 2 tokens/block, 2 channels/thread (verified).
// ============================================================================
__device__ inline unsigned int samp2(const unsigned short* __restrict__ v,
                                     int b, int st, int Wl, int Hl,
                                     int x, int y, int hc)
{
    bool valid = (x >= 0) & (x < Wl) & (y >= 0) & (y < Hl);
    int xc = min(max(x, 0), Wl - 1);
    int yc = min(max(y, 0), Hl - 1);
    size_t idx = ((size_t)(b * S_ + st + yc * Wl + xc)) * 256 + hc;
    unsigned int val = *reinterpret_cast<const unsigned int*>(v + idx);
    return valid ? val : 0u;
}

__global__ __launch_bounds__(256) void deform_k(const float* __restrict__ rp,
                                                const float* __restrict__ oa,
                                                const unsigned short* __restrict__ value,
                                                unsigned short* __restrict__ ca)
{
    const int tk = threadIdx.x >> 7;
    const int tok = blockIdx.x * 2 + tk;
    const int b = tok / NQ_;
    const int h = (threadIdx.x >> 4) & 7;
    const int cp = threadIdx.x & 15;
    const int hc = h * 32 + cp * 2;

    const float* awp = oa + (size_t)tok * 384 + 256 + h * 16;
    float w[16];
    float mx = -1e30f;
    #pragma unroll
    for (int i = 0; i < 16; i++) { w[i] = awp[i]; mx = fmaxf(mx, w[i]); }
    float sum = 0.f;
    #pragma unroll
    for (int i = 0; i < 16; i++) { w[i] = __expf(w[i] - mx); sum += w[i]; }
    const float inv = 1.f / sum;

    const float* rpp  = rp + (size_t)tok * (L_ * 4);
    const float* offp = oa + (size_t)tok * 384 + h * 32;

    const int lvlW[4] = {128, 64, 32, 16};
    const int lvlS[4] = {0, 16384, 20480, 21504};

    float acc0 = 0.f, acc1 = 0.f;
    #pragma unroll
    for (int l = 0; l < 4; l++) {
        const int Wl = lvlW[l], Hl = lvlW[l], st = lvlS[l];
        const float cx = rpp[l * 4 + 0], cy = rpp[l * 4 + 1];
        const float cw = rpp[l * 4 + 2], chh = rpp[l * 4 + 3];
        #pragma unroll
        for (int p = 0; p < 4; p++) {
            float ox = offp[l * 8 + p * 2 + 0];
            float oy = offp[l * 8 + p * 2 + 1];
            float lx = (cx + ox * 0.25f * cw * 0.5f) * Wl - 0.5f;
            float ly = (cy + oy * 0.25f * chh * 0.5f) * Hl - 0.5f;
            float x0f = floorf(lx), y0f = floorf(ly);
            float tx = lx - x0f, ty = ly - y0f;
            int x0 = (int)x0f, y0 = (int)y0f;
            unsigned int u00 = samp2(value, b, st, Wl, Hl, x0,     y0,     hc);
            unsigned int u01 = samp2(value, b, st, Wl, Hl, x0 + 1, y0,     hc);
            unsigned int u10 = samp2(value, b, st, Wl, Hl, x0,     y0 + 1, hc);
            unsigned int u11 = samp2(value, b, st, Wl, Hl, x0 + 1, y0 + 1, hc);
            float w00 = (1.f - tx) * (1.f - ty), w01 = tx * (1.f - ty);
            float w10 = (1.f - tx) * ty,         w11 = tx * ty;
            float g0 = bf16_bits_to_f32((unsigned short)u00) * w00
                     + bf16_bits_to_f32((unsigned short)u01) * w01
                     + bf16_bits_to_f32((unsigned short)u10) * w10
                     + bf16_bits_to_f32((unsigned short)u11) * w11;
            float g1 = bf16_bits_to_f32((unsigned short)(u00 >> 16)) * w00
                     + bf16_bits_to_f32((unsigned short)(u01 >> 16)) * w01
                     + bf16_bits_to_f32((unsigned short)(u10 >> 16)) * w10
                     + bf16_bits_to_f32((unsigned short)(u11 >> 16)) * w11;
            float wa = w[l * 4 + p] * inv;
            acc0 += wa * g0;
            acc1 += wa * g1;
        }
    }
    unsigned int packed = ((unsigned)f32_to_bf16_bits(acc0)) | (((unsigned)f32_to_bf16_bits(acc1)) << 16);
    *reinterpret_cast<unsigned int*>(ca + (size_t)tok * 256 + hc) = packed;
}

// ============================================================================
extern "C" void kernel_launch(void* const* d_in, const int* in_sizes, int n_in,
                              void* d_out, int out_size, void* d_ws, size_t ws_size,
                              hipStream_t stream)
{
    const float* query      = (const float*)d_in[0];
    const float* query_pos  = (const float*)d_in[1];
    const float* ref_pts    = (const float*)d_in[2];
    const float* input_flat = (const float*)d_in[3];
    const float* Wq = (const float*)d_in[6];  const float* bq = (const float*)d_in[7];
    const float* Wk = (const float*)d_in[8];  const float* bk = (const float*)d_in[9];
    const float* Wv = (const float*)d_in[10]; const float* bv = (const float*)d_in[11];
    const float* Wo = (const float*)d_in[12]; const float* bo = (const float*)d_in[13];
    const float* ln1g = (const float*)d_in[14]; const float* ln1b = (const float*)d_in[15];
    const float* W_off = (const float*)d_in[16]; const float* b_off = (const float*)d_in[17];
    const float* W_attn = (const float*)d_in[18]; const float* b_attn = (const float*)d_in[19];
    const float* W_val = (const float*)d_in[20]; const float* b_val = (const float*)d_in[21];
    const float* W_cout = (const float*)d_in[22]; const float* b_cout = (const float*)d_in[23];
    const float* ln2g = (const float*)d_in[24]; const float* ln2b = (const float*)d_in[25];
    const float* W1 = (const float*)d_in[26]; const float* b1 = (const float*)d_in[27];
    const float* W2 = (const float*)d_in[28]; const float* b2 = (const float*)d_in[29];
    const float* ln3g = (const float*)d_in[30]; const float* ln3b = (const float*)d_in[31];
    float* out = (float*)d_out;

    // ---- workspace arena ----
    char* base = (char*)d_ws;
    size_t off = 0;
    auto alloc = [&](size_t bytes) { void* p = base + off; off += (bytes + 255) & ~(size_t)255; return p; };
    unsigned short* value_bf = (unsigned short*)alloc((size_t)B_ * S_ * 256 * 2);   // 89.1 MB
    unsigned short* qk_bf = (unsigned short*)alloc((size_t)NTOK * 1024 * 2);        // qk ∪ h_bf
    unsigned short* h_bf = qk_bf;
    unsigned short* vt = (unsigned short*)alloc((size_t)B_ * 256 * 1024 * 2);       // 4.2 MB
    float* oa_buf = (float*)alloc((size_t)NTOK * 384 * 4);
    float* tmp0   = (float*)alloc((size_t)NTOK * 256 * 4);
    float* x1     = (float*)alloc((size_t)NTOK * 256 * 4);
    float* x2     = (float*)alloc((size_t)NTOK * 256 * 4);
    unsigned short* sc_bf  = (unsigned short*)alloc((size_t)NTOK * 256 * 2);
    unsigned short* q_bf   = (unsigned short*)alloc((size_t)NTOK * 256 * 2);
    unsigned short* qp_bf  = (unsigned short*)alloc((size_t)NTOK * 256 * 2);
    unsigned short* x1p_bf = (unsigned short*)alloc((size_t)NTOK * 256 * 2);
    unsigned short* x2_bf  = (unsigned short*)alloc((size_t)NTOK * 256 * 2);
    unsigned short* wqkv  = (unsigned short*)alloc(768 * 256 * 2);
    unsigned short* wo    = (unsigned short*)alloc(256 * 256 * 2);
    unsigned short* woa   = (unsigned short*)alloc(384 * 256 * 2);
    unsigned short* wval  = (unsigned short*)alloc(256 * 256 * 2);
    unsigned short* wcout = (unsigned short*)alloc(256 * 256 * 2);
    unsigned short* w1t   = (unsigned short*)alloc(1024 * 256 * 2);
    unsigned short* w2t   = (unsigned short*)alloc(256 * 1024 * 2);
    float* qkvbias = (float*)alloc(768 * 4);
    float* oabias  = (float*)alloc(384 * 4);

    dim3 blk(256);

    // ---- fused prep ----
    PrepArgs P;
    P.wsrc[0] = Wq;    P.wdst[0] = wqkv;              P.wK[0] = 256;  P.wN[0] = 256;
    P.wsrc[1] = Wk;    P.wdst[1] = wqkv + 256 * 256;  P.wK[1] = 256;  P.wN[1] = 256;
    P.wsrc[2] = Wv;    P.wdst[2] = wqkv + 512 * 256;  P.wK[2] = 256;  P.wN[2] = 256;
    P.wsrc[3] = Wo;    P.wdst[3] = wo;                P.wK[3] = 256;  P.wN[3] = 256;
    P.wsrc[4] = W_off; P.wdst[4] = woa;               P.wK[4] = 256;  P.wN[4] = 256;
    P.wsrc[5] = W_attn;P.wdst[5] = woa + 256 * 256;   P.wK[5] = 256;  P.wN[5] = 128;
    P.wsrc[6] = W_val; P.wdst[6] = wval;              P.wK[6] = 256;  P.wN[6] = 256;
    P.wsrc[7] = W_cout;P.wdst[7] = wcout;             P.wK[7] = 256;  P.wN[7] = 256;
    P.wsrc[8] = W1;    P.wdst[8] = w1t;               P.wK[8] = 256;  P.wN[8] = 1024;
    P.wsrc[9] = W2;    P.wdst[9] = w2t;               P.wK[9] = 1024; P.wN[9] = 256;
    P.bq = bq; P.bk = bk; P.bv = bv; P.boff = b_off; P.battn = b_attn;
    P.qkvb = qkvbias; P.oab = oabias;
    P.query = query; P.qpos = query_pos; P.q_bf = q_bf; P.qp_bf = qp_bf;
    prep_k<<<891, blk, 0, stream>>>(P);

    // ---- self-attention block ----
    qkv_gemm<<<dim3(12, 125), blk, 0, stream>>>(qp_bf, q_bf, wqkv, qkvbias, qk_bf, vt);
    fattn_k<<<dim3(16, NH_, B_), blk, 0, stream>>>(qk_bf, vt, sc_bf);
    bgemm<false, 0,  64, 256><<<dim3(4, 125), blk, 0, stream>>>(sc_bf, wo, bo, tmp0, nullptr, 256);
    ln_k<2><<<NTOK / 4, blk, 0, stream>>>(query, tmp0, query_pos, ln1g, ln1b, x1, x1p_bf);

    // ---- deformable cross-attention ----
    vgemmF<<<dim3(2, 1360), blk, 0, stream>>>(input_flat, wval, b_val, value_bf);
    bgemm<false, 0,  64, 256><<<dim3(6, 125), blk, 0, stream>>>(x1p_bf, woa, oabias, oa_buf, nullptr, 384);
    deform_k<<<NTOK / 2, blk, 0, stream>>>(ref_pts, oa_buf, value_bf, sc_bf);
    bgemm<false, 0,  64, 256><<<dim3(4, 125), blk, 0, stream>>>(sc_bf, wcout, b_cout, tmp0, nullptr, 256);
    ln_k<1><<<NTOK / 4, blk, 0, stream>>>(x1, tmp0, nullptr, ln2g, ln2b, x2, x2_bf);

    // ---- FFN ----
    bgemm<true,  1,  64, 256><<<dim3(16, 125), blk, 0, stream>>>(x2_bf, w1t, b1, nullptr, h_bf, 1024);
    bgemm<false, 0,  32, 1024><<<dim3(8, 125), blk, 0, stream>>>(h_bf, w2t, b2, tmp0, nullptr, 256);
    ln_k<0><<<NTOK / 4, blk, 0, stream>>>(x2, tmp0, nullptr, ln3g, ln3b, out, nullptr);
}